// Round 5
// baseline (24689.836 us; speedup 1.0000x reference)
//
#include <hip/hip_runtime.h>
#include <hip/hip_bf16.h>
#include <hip/hip_cooperative_groups.h>

namespace cg = cooperative_groups;

#define SS 50
#define TT 50
#define BB 64
#define TRGV 23262
#define EE 300
#define EH 512
#define DH 1024
#define DKPAD 2368   // c_t(1024) | e(300) | h(1024) | pad(20)

// generator GEMM geometry (bf16 MFMA)
#define GMRE 3136
#define GMP 3200
#define GK 1024
#define GNRE TRGV
#define GNP 23296

typedef short bf16x8 __attribute__((ext_vector_type(8)));
typedef float f32x4 __attribute__((ext_vector_type(4)));

__device__ __forceinline__ void glds16(const void* g, void* l) {
  __builtin_amdgcn_global_load_lds(
      (const __attribute__((address_space(1))) void*)g,
      (__attribute__((address_space(3))) void*)l, 16, 0, 0);
}

__device__ __forceinline__ float sigm(float x) { return 1.f / (1.f + expf(-x)); }

__global__ void k_zero(float* __restrict__ p, long n) {
  long i = (long)blockIdx.x * 256 + threadIdx.x;
  if (i < n) p[i] = 0.f;
}

__global__ void k_zero_bf(__hip_bfloat16* __restrict__ p, long n) {
  long i = (long)blockIdx.x * 256 + threadIdx.x;
  if (i < n) p[i] = __float2bfloat16(0.f);
}

__global__ void k_embed(const int* __restrict__ src, const float* __restrict__ emb,
                        float* __restrict__ x) {
  int id = blockIdx.x * 256 + threadIdx.x;
  if (id >= SS * BB * EE) return;
  int sb = id / EE, e = id % EE;
  x[id] = emb[(long)src[sb] * EE + e];
}

// Wcat[row, 0:1324]=dec_W_ih ; [1324:2348]=dec_W_hh ; [2348:2368]=0 (natural rows)
__global__ void k_wcat(const float* __restrict__ Wih, const float* __restrict__ Whh,
                       float* __restrict__ Wcat) {
  long id = (long)blockIdx.x * 256 + threadIdx.x;
  if (id >= (long)4096 * DKPAD) return;
  int row = id / DKPAD, k = id % DKPAD;
  float v;
  if (k < 1324) v = Wih[(long)row * 1324 + k];
  else if (k < 2348) v = Whh[(long)row * 1024 + (k - 1324)];
  else v = 0.f;
  Wcat[id] = v;
}

__global__ void k_transpose(const float* __restrict__ A, float* __restrict__ AT, int n) {
  long id = (long)blockIdx.x * 256 + threadIdx.x;
  if (id >= (long)n * n) return;
  int j = id / n, k = id % n;
  AT[id] = A[(long)k * n + j];  // AT[j][k] = A[k][j]
}

// plain bf16 with zero row padding (generator weight)
__global__ void k_tobf16_pad(const float* __restrict__ W, __hip_bfloat16* __restrict__ Wb,
                             long nrow_real, long nrow_pad, int K) {
  long id = (long)blockIdx.x * 256 + threadIdx.x;
  if (id >= nrow_pad * K) return;
  long r = id / K;
  Wb[id] = __float2bfloat16(r < nrow_real ? W[id] : 0.f);
}

// generic tiled fp32 GEMM: C[M,N] = A[M,K] * W[N,K]^T (+bias), strided.
__global__ __launch_bounds__(256) void k_gemm_big(
    const float* __restrict__ A, const float* __restrict__ W,
    const float* __restrict__ bias, float* __restrict__ C,
    int M, int N, int K, int lda, int ldw, int ldc, int rev) {
  __shared__ float As[16][65];
  __shared__ float Bs[16][65];
  int tid = threadIdx.x;
  int tx = tid & 15, ty = tid >> 4;
  int m0 = blockIdx.y * 64, n0 = blockIdx.x * 64;
  int Srows = M >> 6;
  float acc[4][4] = {};
  for (int k0 = 0; k0 < K; k0 += 16) {
    for (int i = 0; i < 4; ++i) {
      int idx = tid + 256 * i;
      int r = idx >> 4, kk = idx & 15;
      int m = m0 + r;
      float v = 0.f;
      if (m < M && k0 + kk < K) {
        int ar = rev ? (((Srows - 1 - (m >> 6)) << 6) + (m & 63)) : m;
        v = A[(long)ar * lda + k0 + kk];
      }
      As[kk][r] = v;
    }
    for (int i = 0; i < 4; ++i) {
      int idx = tid + 256 * i;
      int r = idx >> 4, kk = idx & 15;
      int n = n0 + r;
      float v = 0.f;
      if (n < N && k0 + kk < K) v = W[(long)n * ldw + k0 + kk];
      Bs[kk][r] = v;
    }
    __syncthreads();
    for (int kk = 0; kk < 16; ++kk) {
      float a[4], bv[4];
      for (int r = 0; r < 4; ++r) a[r] = As[kk][ty * 4 + r];
      for (int c = 0; c < 4; ++c) bv[c] = Bs[kk][tx * 4 + c];
      for (int r = 0; r < 4; ++r)
        for (int c = 0; c < 4; ++c) acc[r][c] += a[r] * bv[c];
    }
    __syncthreads();
  }
  for (int r = 0; r < 4; ++r) {
    int m = m0 + ty * 4 + r;
    if (m >= M) continue;
    for (int c = 0; c < 4; ++c) {
      int n = n0 + tx * 4 + c;
      if (n >= N) continue;
      float v = acc[r][c];
      if (bias) v += bias[n];
      C[(long)m * ldc + n] = v;
    }
  }
}

// ---- persistent encoder: 50 LSTM steps, both directions, 1 grid-sync/step ----
// grid 256x256. blocks 0-127: fwd (j0=(blk)*4), 128-255: bwd.
__global__ __launch_bounds__(256) void persist_enc(
    const float* __restrict__ xW_f, const float* __restrict__ xW_b,
    const float* __restrict__ Whf, const float* __restrict__ Whb,
    float* __restrict__ hs, float* hA, float* hB, float* hA2, float* hB2,
    float* __restrict__ cf, float* __restrict__ cb,
    float* __restrict__ h0out, float* __restrict__ c0out) {
  cg::grid_group gg = cg::this_grid();
  __shared__ float As[64][65];
  __shared__ float Ws[16][64];
  int tid = threadIdx.x;
  int b = tid & 63, jj = tid >> 6;
  int blk = blockIdx.x;
  int dir = blk >> 7;
  int j0 = (blk & 127) * 4;
  const float* Whh = dir ? Whb : Whf;
  float* c = dir ? cb : cf;
  const float* xWbase = dir ? xW_b : xW_f;
  float* hp = dir ? hA2 : hA;
  float* hn = dir ? hB2 : hB;

  for (int s = 0; s < SS; ++s) {
    const float* xW = xWbase + (long)s * BB * 2048;
    float* hs_dst = dir ? (hs + (long)(SS - 1 - s) * BB * DH + EH)
                        : (hs + (long)s * BB * DH);
    float acc[4] = {0.f, 0.f, 0.f, 0.f};
    for (int c0 = 0; c0 < EH; c0 += 64) {
      for (int i = 0; i < 16; ++i) {
        int idx = tid + 256 * i;
        int r = idx >> 6, kk = idx & 63;
        As[r][kk] = hp[r * EH + c0 + kk];
      }
      for (int i = 0; i < 4; ++i) {
        int idx = tid + 256 * i;
        int r = idx >> 6, kk = idx & 63;
        int grow = j0 + (r & 3) + (r >> 2) * EH;
        Ws[r][kk] = Whh[(long)grow * EH + c0 + kk];
      }
      __syncthreads();
      for (int kk = 0; kk < 64; ++kk) {
        float a = As[b][kk];
        acc[0] += a * Ws[jj][kk];
        acc[1] += a * Ws[4 + jj][kk];
        acc[2] += a * Ws[8 + jj][kk];
        acc[3] += a * Ws[12 + jj][kk];
      }
      __syncthreads();
    }
    int j = j0 + jj;
    float gi = acc[0] + xW[b * 2048 + j];
    float gf = acc[1] + xW[b * 2048 + j + 512];
    float gg2 = acc[2] + xW[b * 2048 + j + 1024];
    float go = acc[3] + xW[b * 2048 + j + 1536];
    float ii = sigm(gi), ff = sigm(gf), gt = tanhf(gg2), oo = sigm(go);
    float cn = ff * c[b * EH + j] + ii * gt;
    float hnv = oo * tanhf(cn);
    c[b * EH + j] = cn;
    hn[b * EH + j] = hnv;
    hs_dst[b * DH + j] = hnv;
    float* t = hp; hp = hn; hn = t;
    gg.sync();
  }
  // build decoder initial state (reshape(stack([hf,hb]),(64,1024)) remap).
  // After 50 swaps final fwd h is in hA, bwd in hA2.
  int gid = blk * 256 + tid;
  int dd = gid >> 15, bb2 = (gid >> 9) & 63, j2 = gid & 511;
  h0out[gid] = (dd ? hA2 : hA)[bb2 * EH + j2];
  c0out[gid] = (dd ? cb : cf)[bb2 * EH + j2];
}

// ---- persistent decoder: 49 steps, 4 phases (4 grid-syncs) per step ----
// grid 256x256, all fp32.
__global__ __launch_bounds__(256) void persist_dec(
    const float* __restrict__ G, const float* __restrict__ hs,
    const float* __restrict__ Wo, const float* __restrict__ Wcat,
    const float* __restrict__ db, const float* __restrict__ emb_de,
    const int* __restrict__ trg,
    float* hd0, float* hd1, float* __restrict__ cd,
    float* __restrict__ attw, float* __restrict__ stb, float* __restrict__ ctb,
    float* __restrict__ ebuf, __hip_bfloat16* __restrict__ A_bf) {
  cg::grid_group gg = cg::this_grid();
  __shared__ float As[64][65];
  __shared__ float Ws[16][64];
  __shared__ float sc[64];
  int tid = threadIdx.x;
  int blk = blockIdx.x;
  int b = tid & 63, jj = tid >> 6;
  int gid = blk * 256 + tid;
  float* hcur = hd0;
  float* hnext = hd1;

  for (int t = 0; t < TT - 1; ++t) {
    // Phase S: scores[s,b] = h[b,:]·G[s,b,:]; softmax over b (axis=1!)
    if (blk < SS) {
      int s = blk;
      int bb = tid >> 2, l = tid & 3;
      const float* Grow = G + ((long)s * BB + bb) * DH;
      const float* hrow = hcur + bb * DH;
      float pp = 0.f;
      for (int d = l; d < DH; d += 4) pp += hrow[d] * Grow[d];
      pp += __shfl_xor(pp, 1);
      pp += __shfl_xor(pp, 2);
      if (l == 0) sc[bb] = pp;
      __syncthreads();
      if (tid < 64) {
        float v = sc[tid];
        float m = v;
        for (int o = 32; o > 0; o >>= 1) m = fmaxf(m, __shfl_xor(m, o));
        float e = expf(v - m);
        float su = e;
        for (int o = 32; o > 0; o >>= 1) su += __shfl_xor(su, o);
        attw[s * BB + tid] = e / su;
      }
    }
    gg.sync();
    // Phase T: st[b,d] = sum_s attw[s,b]*hs[s,b,d]; gather e for this step
    {
      int bb = gid >> 10, d = gid & 1023;
      float acc = 0.f;
      for (int s = 0; s < SS; ++s)
        acc += attw[s * BB + bb] * hs[(long)s * (BB * DH) + bb * DH + d];
      stb[gid] = acc;
      if (gid < BB * EE) {
        int rb = gid / EE, rj = gid % EE;
        ebuf[rb * EE + rj] = emb_de[(long)trg[t * BB + rb] * EE + rj];
      }
    }
    gg.sync();
    // Phase C: ct[b,n] = tanh([st|h][b,:] @ Wo[n,:]) ; block covers n0..n0+3
    {
      int n0 = blk * 4;
      float acc = 0.f;
      for (int cc = 0; cc < 32; ++cc) {
        const float* Asrc = (cc < 16) ? stb : hcur;
        int c0 = (cc & 15) * 64;
        for (int i = 0; i < 16; ++i) {
          int idx = tid + 256 * i;
          int r = idx >> 6, kk = idx & 63;
          As[r][kk] = Asrc[r * DH + c0 + kk];
        }
        {
          int r = tid >> 6, kk = tid & 63;
          Ws[r][kk] = Wo[(long)(n0 + r) * (2 * DH) + cc * 64 + kk];
        }
        __syncthreads();
        for (int kk = 0; kk < 64; ++kk) acc += As[b][kk] * Ws[jj][kk];
        __syncthreads();
      }
      ctb[b * DH + n0 + jj] = tanhf(acc);
    }
    gg.sync();
    // Phase G: gates = [ct|e|h] @ Wcat^T + db ; LSTM pointwise; h -> hnext + A_bf
    {
      int j0 = blk * 4;
      float acc[4] = {0.f, 0.f, 0.f, 0.f};
      for (int cc = 0; cc < DKPAD / 64; ++cc) {
        int c0 = cc * 64;
        for (int i = 0; i < 16; ++i) {
          int idx = tid + 256 * i;
          int r = idx >> 6, kk = idx & 63;
          int col = c0 + kk;
          float v;
          if (col < 1024) v = ctb[r * DH + col];
          else if (col < 1324) v = ebuf[r * EE + col - 1024];
          else if (col < 2348) v = hcur[r * DH + col - 1324];
          else v = 0.f;
          As[r][kk] = v;
        }
        for (int i = 0; i < 4; ++i) {
          int idx = tid + 256 * i;
          int r = idx >> 6, kk = idx & 63;
          int grow = j0 + (r & 3) + (r >> 2) * 1024;
          Ws[r][kk] = Wcat[(long)grow * DKPAD + c0 + kk];
        }
        __syncthreads();
        for (int kk = 0; kk < 64; ++kk) {
          float a = As[b][kk];
          acc[0] += a * Ws[jj][kk];
          acc[1] += a * Ws[4 + jj][kk];
          acc[2] += a * Ws[8 + jj][kk];
          acc[3] += a * Ws[12 + jj][kk];
        }
        __syncthreads();
      }
      int j = j0 + jj;
      float gi = acc[0] + db[j];
      float gf = acc[1] + db[j + 1024];
      float gg2 = acc[2] + db[j + 2048];
      float go = acc[3] + db[j + 3072];
      float ii = sigm(gi), ff = sigm(gf), gt = tanhf(gg2), oo = sigm(go);
      float cn = ff * cd[b * DH + j] + ii * gt;
      float hnv = oo * tanhf(cn);
      cd[b * DH + j] = cn;
      hnext[b * DH + j] = hnv;
      A_bf[(long)t * (BB * DH) + b * DH + j] = __float2bfloat16(hnv);
    }
    float* tmp = hcur; hcur = hnext; hnext = tmp;
    gg.sync();
  }
}

// ---- bf16 MFMA generator GEMM (128x128 tile, m97 structure) ----
__global__ __launch_bounds__(256) void k_gen_mfma(
    const __hip_bfloat16* __restrict__ A, const __hip_bfloat16* __restrict__ Bw,
    const float* __restrict__ bias, float* __restrict__ C) {
  __shared__ __hip_bfloat16 As[128 * 32];
  __shared__ __hip_bfloat16 Bs[128 * 32];
  int tid = threadIdx.x;
  int lane = tid & 63, w = tid >> 6;
  long m0 = (long)blockIdx.y * 128, n0 = (long)blockIdx.x * 128;

  int srow = lane >> 2;
  int scol = (lane & 3) * 8;
  const __hip_bfloat16* gA0 = A + (m0 + w * 32 + srow) * GK + scol;
  const __hip_bfloat16* gA1 = gA0 + 16 * GK;
  const __hip_bfloat16* gB0 = Bw + (n0 + w * 32 + srow) * GK + scol;
  const __hip_bfloat16* gB1 = gB0 + 16 * GK;
  char* lA0 = (char*)As + w * 2048;
  char* lA1 = lA0 + 1024;
  char* lB0 = (char*)Bs + w * 2048;
  char* lB1 = lB0 + 1024;

  int wm = (w >> 1) * 64, wn = (w & 1) * 64;
  int fr = lane & 15;
  int kc = (lane >> 4) * 8;
  f32x4 acc[4][4] = {};

  for (int kt = 0; kt < GK / 32; ++kt) {
    int k0 = kt * 32;
    glds16(gA0 + k0, lA0);
    glds16(gA1 + k0, lA1);
    glds16(gB0 + k0, lB0);
    glds16(gB1 + k0, lB1);
    __syncthreads();
    bf16x8 a[4], b[4];
    for (int mi = 0; mi < 4; ++mi)
      a[mi] = *(const bf16x8*)(As + (wm + mi * 16 + fr) * 32 + kc);
    for (int ni = 0; ni < 4; ++ni)
      b[ni] = *(const bf16x8*)(Bs + (wn + ni * 16 + fr) * 32 + kc);
    for (int mi = 0; mi < 4; ++mi)
      for (int ni = 0; ni < 4; ++ni)
        acc[mi][ni] = __builtin_amdgcn_mfma_f32_16x16x32_bf16(a[mi], b[ni], acc[mi][ni], 0, 0, 0);
    __syncthreads();
  }

  for (int mi = 0; mi < 4; ++mi) {
    for (int ni = 0; ni < 4; ++ni) {
      int n = (int)n0 + wn + ni * 16 + (lane & 15);
      if (n >= GNRE) continue;
      float bv = bias[n];
      for (int r = 0; r < 4; ++r) {
        int m = (int)m0 + wm + mi * 16 + (lane >> 4) * 4 + r;
        if (m < GMRE) C[(long)m * TRGV + n] = acc[mi][ni][r] + bv;
      }
    }
  }
}

// in-place log-softmax over vocab for rows 64..3199 of out
__global__ __launch_bounds__(256) void k_logsoftmax(float* __restrict__ out) {
  int r = blockIdx.x;
  float* p = out + (long)(BB + r) * TRGV;
  int tid = threadIdx.x;
  __shared__ float red[256];
  float m = -1e30f;
  for (int i = tid; i < TRGV; i += 256) m = fmaxf(m, p[i]);
  red[tid] = m;
  __syncthreads();
  for (int s = 128; s > 0; s >>= 1) {
    if (tid < s) red[tid] = fmaxf(red[tid], red[tid + s]);
    __syncthreads();
  }
  m = red[0];
  __syncthreads();
  float sum = 0.f;
  for (int i = tid; i < TRGV; i += 256) sum += expf(p[i] - m);
  red[tid] = sum;
  __syncthreads();
  for (int s = 128; s > 0; s >>= 1) {
    if (tid < s) red[tid] += red[tid + s];
    __syncthreads();
  }
  float lse = m + logf(red[0]);
  for (int i = tid; i < TRGV; i += 256) p[i] -= lse;
}

extern "C" void kernel_launch(void* const* d_in, const int* in_sizes, int n_in,
                              void* d_out, int out_size, void* d_ws, size_t ws_size,
                              hipStream_t stream) {
  const int* src = (const int*)d_in[0];
  const int* trg = (const int*)d_in[1];
  const float* emb_en = (const float*)d_in[2];
  const float* emb_de = (const float*)d_in[3];
  const float* eWih_f = (const float*)d_in[4];
  const float* eWhh_f = (const float*)d_in[5];
  const float* eb_f = (const float*)d_in[6];
  const float* eWih_b = (const float*)d_in[7];
  const float* eWhh_b = (const float*)d_in[8];
  const float* eb_b = (const float*)d_in[9];
  const float* dWih = (const float*)d_in[10];
  const float* dWhh = (const float*)d_in[11];
  const float* db = (const float*)d_in[12];
  const float* Wgen = (const float*)d_in[13];
  const float* bgen = (const float*)d_in[14];
  const float* Wi = (const float*)d_in[15];
  const float* Wo = (const float*)d_in[16];
  float* out = (float*)d_out;

  float* base = (float*)d_ws;
  // region: x_enc | xW_f | xW_b  (freed after persist_enc; reused for Wgen_bf + WiT)
  float* x_enc = base;                                   // 960,000
  float* xW_f = base + 960000;                           // 6,553,600
  float* xW_b = xW_f + (long)6553600;                    // 6,553,600
  __hip_bfloat16* Wgen_bf = (__hip_bfloat16*)base;       // 23,855,104 bf16 (after enc)
  float* WiT = base + 12000000;                          // 1,048,576 (after enc)
  float* p = base + 14067200;
  float* hs = p; p += (long)SS * BB * DH;                // 3,276,800
  float* G = p; p += (long)SS * BB * DH;                 // 3,276,800
  float* Wcat = p; p += (long)4096 * DKPAD;              // 9,699,328
  __hip_bfloat16* A_bf = (__hip_bfloat16*)p; p += (GMP * GK) / 2;  // 1,638,400 fl
  float* hA = p; p += BB * EH;
  float* hB = p; p += BB * EH;
  float* hA2 = p; p += BB * EH;
  float* hB2 = p; p += BB * EH;
  float* cf = p; p += BB * EH;
  float* cb = p; p += BB * EH;
  float* hd0 = p; p += BB * DH;
  float* hd1 = p; p += BB * DH;
  float* cd = p; p += BB * DH;
  float* stb = p; p += BB * DH;
  float* ctb = p; p += BB * DH;
  float* attw = p; p += SS * BB;
  float* ebuf = p; p += BB * EE;

  dim3 b256(256);

  // ---- setup ----
  k_embed<<<dim3((SS * BB * EE + 255) / 256), b256, 0, stream>>>(src, emb_en, x_enc);
  k_wcat<<<dim3((int)(((long)4096 * DKPAD + 255) / 256)), b256, 0, stream>>>(dWih, dWhh, Wcat);
  k_zero<<<dim3((6 * BB * EH + 255) / 256), b256, 0, stream>>>(hA, 6 * BB * EH);  // hA..cb
  k_zero<<<dim3((int)(((long)BB * TRGV + 255) / 256)), b256, 0, stream>>>(out, (long)BB * TRGV);
  k_zero_bf<<<dim3(((GMP - GMRE) * GK + 255) / 256), b256, 0, stream>>>(
      A_bf + (long)GMRE * GK, (long)(GMP - GMRE) * GK);

  // ---- encoder input GEMMs: xW = x @ W_ih^T + b ----
  k_gemm_big<<<dim3(2048 / 64, (SS * BB) / 64), b256, 0, stream>>>(
      x_enc, eWih_f, eb_f, xW_f, SS * BB, 2048, EE, EE, EE, 2048, 0);
  k_gemm_big<<<dim3(2048 / 64, (SS * BB) / 64), b256, 0, stream>>>(
      x_enc, eWih_b, eb_b, xW_b, SS * BB, 2048, EE, EE, EE, 2048, 1);

  // ---- persistent encoder (cooperative) ----
  {
    void* args[] = {(void*)&xW_f, (void*)&xW_b, (void*)&eWhh_f, (void*)&eWhh_b,
                    (void*)&hs, (void*)&hA, (void*)&hB, (void*)&hA2, (void*)&hB2,
                    (void*)&cf, (void*)&cb, (void*)&hd0, (void*)&cd};
    hipLaunchCooperativeKernel((const void*)persist_enc, dim3(256), dim3(256),
                               args, 0, stream);
  }

  // ---- post-encoder prep: WiT, G = hs @ Wi, Wgen -> bf16 (region reuse) ----
  k_transpose<<<dim3((int)(((long)DH * DH + 255) / 256)), b256, 0, stream>>>(Wi, WiT, DH);
  k_gemm_big<<<dim3(DH / 64, (SS * BB) / 64), b256, 0, stream>>>(
      hs, WiT, (const float*)nullptr, G, SS * BB, DH, DH, DH, DH, DH, 0);
  k_tobf16_pad<<<dim3((int)(((long)GNP * GK + 255) / 256)), b256, 0, stream>>>(
      Wgen, Wgen_bf, GNRE, GNP, GK);

  // ---- persistent decoder (cooperative) ----
  {
    void* args[] = {(void*)&G, (void*)&hs, (void*)&Wo, (void*)&Wcat, (void*)&db,
                    (void*)&emb_de, (void*)&trg, (void*)&hd0, (void*)&hd1,
                    (void*)&cd, (void*)&attw, (void*)&stb, (void*)&ctb,
                    (void*)&ebuf, (void*)&A_bf};
    hipLaunchCooperativeKernel((const void*)persist_dec, dim3(256), dim3(256),
                               args, 0, stream);
  }

  // ---- generator: bf16 MFMA GEMM + log-softmax ----
  k_gen_mfma<<<dim3(GNP / 128, GMP / 128), b256, 0, stream>>>(
      A_bf, Wgen_bf, bgen, out + (long)BB * TRGV);
  k_logsoftmax<<<dim3((TT - 1) * BB), b256, 0, stream>>>(out);
}

// Round 7
// 12230.315 us; speedup vs baseline: 2.0187x; 2.0187x over previous
//
#include <hip/hip_runtime.h>
#include <hip/hip_bf16.h>
#include <hip/hip_cooperative_groups.h>

namespace cg = cooperative_groups;

#define SS 50
#define TT 50
#define BB 64
#define TRGV 23262
#define EE 300
#define EH 512
#define DH 1024

// generator GEMM geometry (bf16 MFMA)
#define GMRE 3136
#define GMP 3200
#define GK 1024
#define GNRE TRGV
#define GNP 23296

typedef short bf16x8 __attribute__((ext_vector_type(8)));
typedef float f32x4 __attribute__((ext_vector_type(4)));

__device__ __forceinline__ void glds16(const void* g, void* l) {
  __builtin_amdgcn_global_load_lds(
      (const __attribute__((address_space(1))) void*)g,
      (__attribute__((address_space(3))) void*)l, 16, 0, 0);
}

__device__ __forceinline__ float sigm(float x) { return 1.f / (1.f + expf(-x)); }
__device__ __forceinline__ float sum4(f32x4 v) { return v[0] + v[1] + v[2] + v[3]; }

__device__ __forceinline__ void split2(float x, __hip_bfloat16& hi, __hip_bfloat16& lo) {
  hi = __float2bfloat16(x);
  lo = __float2bfloat16(x - __bfloat162float(hi));
}

__global__ void k_zero(float* __restrict__ p, long n) {
  long i = (long)blockIdx.x * 256 + threadIdx.x;
  if (i < n) p[i] = 0.f;
}
__global__ void k_zero_bf(__hip_bfloat16* __restrict__ p, long n) {
  long i = (long)blockIdx.x * 256 + threadIdx.x;
  if (i < n) p[i] = __float2bfloat16(0.f);
}

__global__ void k_embed(const int* __restrict__ src, const float* __restrict__ emb,
                        float* __restrict__ x) {
  int id = blockIdx.x * 256 + threadIdx.x;
  if (id >= SS * BB * EE) return;
  int sb = id / EE, e = id % EE;
  x[id] = emb[(long)src[sb] * EE + e];
}

__global__ void k_dbperm(const float* __restrict__ db, float* __restrict__ dbp) {
  int id = blockIdx.x * 256 + threadIdx.x;
  if (id >= 4096) return;
  int u = id >> 2, g = id & 3;
  dbp[id] = db[g * 1024 + u];
}

// fp32 [rows][ld] (+col_off) -> [rows_pad][2*Kpad] bf16 hi|lo, zero pad.
// mode 0: src=r ; 1: seq-reverse per 64 (50 groups) ; 2: gate-perm rp=4u+g <- g*1024+u
// mode 3: TRANSPOSE (out[r][k] = in[k][r]) — used for Wi so G = hs @ Wi (not Wi^T).
__global__ void k_split_pad(const float* __restrict__ in, int ld_in, int col_off,
                            int Kreal, int Kpad, int rows_real, long rows_pad,
                            int mode, __hip_bfloat16* __restrict__ out) {
  long id = (long)blockIdx.x * 256 + threadIdx.x;
  if (id >= rows_pad * Kpad) return;
  long r = id / Kpad;
  int k = id % Kpad;
  float v = 0.f;
  if (r < rows_real && k < Kreal) {
    if (mode == 3) {
      v = in[(long)k * ld_in + col_off + r];
    } else {
      long sr = r;
      if (mode == 1) sr = ((49 - (r >> 6)) << 6) + (r & 63);
      else if (mode == 2) sr = (long)(r & 3) * 1024 + (r >> 2);
      v = in[sr * ld_in + col_off + k];
    }
  }
  __hip_bfloat16 hi, lo;
  split2(v, hi, lo);
  out[r * 2 * Kpad + k] = hi;
  out[r * 2 * Kpad + Kpad + k] = lo;
}

// gather emb_de[trg[t,b]] -> split [3200][2*320]
__global__ void k_embgather_split(const int* __restrict__ trg, const float* __restrict__ emb,
                                  __hip_bfloat16* __restrict__ out) {
  long id = (long)blockIdx.x * 256 + threadIdx.x;
  if (id >= 3200L * 320) return;
  long r = id / 320;
  int k = id % 320;
  int t = r >> 6, b = r & 63;
  float v = 0.f;
  if (t < TT - 1 && k < EE) v = emb[(long)trg[t * BB + b] * EE + k];
  __hip_bfloat16 hi, lo;
  split2(v, hi, lo);
  out[r * 640 + k] = hi;
  out[r * 640 + 320 + k] = lo;
}

// plain bf16 with zero row padding (generator weight)
__global__ void k_tobf16_pad(const float* __restrict__ W, __hip_bfloat16* __restrict__ Wb,
                             long nrow_real, long nrow_pad, int K) {
  long id = (long)blockIdx.x * 256 + threadIdx.x;
  if (id >= nrow_pad * K) return;
  long r = id / K;
  Wb[id] = __float2bfloat16(r < nrow_real ? W[id] : 0.f);
}

// ---- generic split-bf16 MFMA GEMM (3-pass: AhWh + AlWh + AhWl), 128x128 tile ----
// A2 [Mpad][2*Kpad], W2 [Npad][2*Kpad]; out fp32 (OUTBF=0) or bf16 (OUTBF=1).
template<int OUTBF>
__global__ __launch_bounds__(256) void k_gsplit(
    const __hip_bfloat16* __restrict__ A2, const __hip_bfloat16* __restrict__ W2,
    const float* __restrict__ bias, void* __restrict__ Cout,
    int Mreal, int Nreal, int ldc, int Kpad) {
  __shared__ __hip_bfloat16 As[128 * 32];
  __shared__ __hip_bfloat16 Bs[128 * 32];
  int tid = threadIdx.x, lane = tid & 63, w = tid >> 6;
  long m0 = (long)blockIdx.y * 128, n0 = (long)blockIdx.x * 128;
  int lda2 = 2 * Kpad;
  int srow = lane >> 2;
  int scol = (lane & 3) * 8;
  char* lA0 = (char*)As + w * 2048;
  char* lA1 = lA0 + 1024;
  char* lB0 = (char*)Bs + w * 2048;
  char* lB1 = lB0 + 1024;
  int wm = (w >> 1) * 64, wn = (w & 1) * 64;
  int fr = lane & 15;
  int kc = (lane >> 4) * 8;
  f32x4 acc[4][4] = {};

  for (int seg = 0; seg < 3; ++seg) {
    const __hip_bfloat16* Ab = A2 + (seg == 1 ? Kpad : 0);
    const __hip_bfloat16* Wb = W2 + (seg == 2 ? Kpad : 0);
    const __hip_bfloat16* gA0 = Ab + (m0 + w * 32 + srow) * (long)lda2 + scol;
    const __hip_bfloat16* gA1 = gA0 + 16L * lda2;
    const __hip_bfloat16* gB0 = Wb + (n0 + w * 32 + srow) * (long)lda2 + scol;
    const __hip_bfloat16* gB1 = gB0 + 16L * lda2;
    for (int kt = 0; kt < Kpad / 32; ++kt) {
      int k0 = kt * 32;
      glds16(gA0 + k0, lA0);
      glds16(gA1 + k0, lA1);
      glds16(gB0 + k0, lB0);
      glds16(gB1 + k0, lB1);
      __syncthreads();
      bf16x8 a[4], b[4];
      for (int mi = 0; mi < 4; ++mi)
        a[mi] = *(const bf16x8*)(As + (wm + mi * 16 + fr) * 32 + kc);
      for (int ni = 0; ni < 4; ++ni)
        b[ni] = *(const bf16x8*)(Bs + (wn + ni * 16 + fr) * 32 + kc);
      for (int mi = 0; mi < 4; ++mi)
        for (int ni = 0; ni < 4; ++ni)
          acc[mi][ni] = __builtin_amdgcn_mfma_f32_16x16x32_bf16(a[mi], b[ni], acc[mi][ni], 0, 0, 0);
      __syncthreads();
    }
  }

  for (int mi = 0; mi < 4; ++mi) {
    for (int ni = 0; ni < 4; ++ni) {
      int n = (int)n0 + wn + ni * 16 + (lane & 15);
      if (n >= Nreal) continue;
      float bv = bias ? bias[n] : 0.f;
      for (int r = 0; r < 4; ++r) {
        int m = (int)m0 + wm + mi * 16 + (lane >> 4) * 4 + r;
        if (m >= Mreal) continue;
        float v = acc[mi][ni][r] + bv;
        if (OUTBF) ((__hip_bfloat16*)Cout)[(long)m * ldc + n] = __float2bfloat16(v);
        else ((float*)Cout)[(long)m * ldc + n] = v;
      }
    }
  }
}

// ---- persistent encoder: Whh in LDS, 1 grid-sync/step ----
// grid 256 x 512. blocks 0-127 fwd, 128-255 bwd; each block: 4 units (16 gate rows).
__global__ __launch_bounds__(512) void persist_enc(
    const float* __restrict__ xW_f, const float* __restrict__ xW_b,
    const float* __restrict__ Whf, const float* __restrict__ Whb,
    float* __restrict__ hs, float* hA, float* hB, float* hA2, float* hB2,
    float* __restrict__ cf, float* __restrict__ cb,
    float* __restrict__ hd0, float* __restrict__ hT0, float* __restrict__ cdD) {
  cg::grid_group gg = cg::this_grid();
  __shared__ float WL[16 * 516];
  int t = threadIdx.x;
  int blk = blockIdx.x;
  int dir = blk >> 7, bl = blk & 127;
  const float* Whh = dir ? Whb : Whf;
  const float* xWb0 = dir ? xW_b : xW_f;
  float* c = dir ? cb : cf;
  float* hp = dir ? hA2 : hA;
  float* hn = dir ? hB2 : hB;

  // load Whh slice (gate-permuted rows rp=4ul+g <- g*512 + (bl*4+ul))
  for (int idx = t; idx < 16 * 512; idx += 512) {
    int r = idx >> 9, k = idx & 511;
    int srcrow = (r & 3) * 512 + (bl * 4 + (r >> 2));
    WL[r * 516 + k] = Whh[(long)srcrow * 512 + k];
  }
  __syncthreads();

  int j = t & 15;
  int b0 = t >> 4, b1 = b0 + 32;
  int g = j & 3;
  int ju = bl * 4 + (j >> 2);
  int lbase = (t & 63) & ~3;
  const f32x4* wq = (const f32x4*)(WL + j * 516);

  for (int s = 0; s < SS; ++s) {
    const f32x4* h0q = (const f32x4*)(hp + b0 * 512);
    const f32x4* h1q = (const f32x4*)(hp + b1 * 512);
    f32x4 v0 = {0, 0, 0, 0}, v1 = {0, 0, 0, 0};
    for (int q = 0; q < 128; ++q) {
      f32x4 wv = wq[q];
      v0 += wv * h0q[q];
      v1 += wv * h1q[q];
    }
    const float* xW = xWb0 + (long)(s * BB) * 2048;
    float a0 = sum4(v0) + xW[b0 * 2048 + g * 512 + ju];
    float a1 = sum4(v1) + xW[b1 * 2048 + g * 512 + ju];
    float gi0 = __shfl(a0, lbase + 0), gf0 = __shfl(a0, lbase + 1);
    float gg0 = __shfl(a0, lbase + 2), go0 = __shfl(a0, lbase + 3);
    float gi1 = __shfl(a1, lbase + 0), gf1 = __shfl(a1, lbase + 1);
    float gg1 = __shfl(a1, lbase + 2), go1 = __shfl(a1, lbase + 3);
    if ((t & 3) == 0) {
      long hsrow0, hsrow1;
      int hscol = dir ? (512 + ju) : ju;
      int srow = dir ? (SS - 1 - s) : s;
      hsrow0 = (long)(srow * BB + b0) * DH + hscol;
      hsrow1 = (long)(srow * BB + b1) * DH + hscol;
      float cn0 = sigm(gf0) * c[b0 * 512 + ju] + sigm(gi0) * tanhf(gg0);
      float hn0 = sigm(go0) * tanhf(cn0);
      c[b0 * 512 + ju] = cn0;
      hn[b0 * 512 + ju] = hn0;
      hs[hsrow0] = hn0;
      float cn1 = sigm(gf1) * c[b1 * 512 + ju] + sigm(gi1) * tanhf(gg1);
      float hn1 = sigm(go1) * tanhf(cn1);
      c[b1 * 512 + ju] = cn1;
      hn[b1 * 512 + ju] = hn1;
      hs[hsrow1] = hn1;
    }
    float* tmp = hp; hp = hn; hn = tmp;
    gg.sync();
  }
  // decoder init: flat stack-reshape mapping (50 swaps even -> final in hA/hA2)
  int gid = blk * 512 + t;
  if (gid < 65536) {
    int d2 = gid >> 15, b = (gid >> 9) & 63, j2 = gid & 511;
    float hv = (d2 ? hA2 : hA)[b * 512 + j2];
    float cv = (d2 ? cb : cf)[b * 512 + j2];
    hd0[gid] = hv;
    cdD[gid] = cv;
    int bp = gid >> 10, jp = gid & 1023;
    hT0[jp * 64 + bp] = hv;
  }
}

// ---- persistent decoder: Wc13 + Wo2 slices pinned in LDS, 3 grid-syncs/step ----
// grid 256 x 512. block owns gate-rows 16*blk..+15 (4 units) and ct-cols blk*4..+3.
__global__ __launch_bounds__(512) void persist_dec(
    const float* __restrict__ G, const float* __restrict__ HsWo1,
    const float* __restrict__ Wo, const float* __restrict__ dWih,
    const float* __restrict__ dWhh, const __hip_bfloat16* __restrict__ Eg,
    float* hd0, float* hd1, float* hT0, float* hT1,
    float* __restrict__ cd, float* __restrict__ attw, float* __restrict__ ctb,
    __hip_bfloat16* __restrict__ A_bf) {
  cg::grid_group gg = cg::this_grid();
  __shared__ float WcL[16 * 2052];   // 131,328 B
  __shared__ float WoL[4 * 1028];    //  16,448 B
  __shared__ float red[2048];        //   8,192 B
  int t = threadIdx.x;
  int blk = blockIdx.x;
  int w = t >> 6, lane = t & 63;

  // load Wc13 slice: rows rp = blk*16 + r (gate-perm: rp=4u+g <- g*1024+u);
  // cols 0:1024 = dWih ct-part (ld 1324), 1024:2048 = dWhh (ld 1024)
  for (int idx = t; idx < 16 * 2048; idx += 512) {
    int r = idx >> 11, k = idx & 2047;
    int rp = blk * 16 + r;
    long srcrow = (long)(rp & 3) * 1024 + (rp >> 2);
    float v = (k < 1024) ? dWih[srcrow * 1324 + k] : dWhh[srcrow * 1024 + (k - 1024)];
    WcL[r * 2052 + k] = v;
  }
  // load Wo2 slice: rows blk*4..+3, cols 1024:2048 of Wo (ld 2048)
  for (int idx = t; idx < 4 * 1024; idx += 512) {
    int r = idx >> 10, k = idx & 1023;
    WoL[r * 1028 + k] = Wo[(long)(blk * 4 + r) * 2048 + 1024 + k];
  }
  __syncthreads();

  float* hcur = hd0; float* hnew = hd1;
  float* hTc = hT0;  float* hTn = hT1;
  int j = t & 15;
  int b0 = t >> 4, b1 = b0 + 32;
  int rp = blk * 16 + j;
  int ju = blk * 4 + (j >> 2);
  int lbase = (t & 63) & ~3;

  for (int ts = 0; ts < TT - 1; ++ts) {
    // ---- Phase S: scores[s,b] = h[b,:]·G[s,b,:], softmax over b ----
    if (blk < SS) {
      int s = blk;
      const f32x4* gq = (const f32x4*)(G + ((long)(s * BB + lane)) * DH + w * 128);
      const f32x4* hq = (const f32x4*)(hcur + lane * DH + w * 128);
      f32x4 a4 = {0, 0, 0, 0};
      for (int q = 0; q < 32; ++q) a4 += gq[q] * hq[q];
      red[w * 64 + lane] = sum4(a4);
      __syncthreads();
      if (w == 0) {
        float sc = 0.f;
        for (int i = 0; i < 8; ++i) sc += red[i * 64 + lane];
        float m = sc;
        for (int o = 32; o > 0; o >>= 1) m = fmaxf(m, __shfl_xor(m, o));
        float e = expf(sc - m);
        float su = e;
        for (int o = 32; o > 0; o >>= 1) su += __shfl_xor(su, o);
        attw[s * BB + lane] = e / su;
      }
    }
    gg.sync();
    // ---- Phase TC: ct[b, blk*4+nl] = tanh( sum_s a*HsWo1 + h@Wo2 ) ----
    {
      int n0 = blk * 4;
      f32x4 z = {0, 0, 0, 0};
      for (int s = w; s < SS; s += 8) {
        float aw = attw[s * BB + lane];
        f32x4 hv = *(const f32x4*)(HsWo1 + ((long)(s * BB + lane)) * DH + n0);
        z += aw * hv;
      }
      for (int k = w * 128; k < w * 128 + 128; ++k) {
        float hb = hTc[k * 64 + lane];
        f32x4 wv = {WoL[0 * 1028 + k], WoL[1 * 1028 + k], WoL[2 * 1028 + k], WoL[3 * 1028 + k]};
        z += hb * wv;
      }
      red[w * 256 + lane * 4 + 0] = z[0];
      red[w * 256 + lane * 4 + 1] = z[1];
      red[w * 256 + lane * 4 + 2] = z[2];
      red[w * 256 + lane * 4 + 3] = z[3];
      __syncthreads();
      if (t < 256) {
        int b = t >> 2, nl = t & 3;
        float sv = 0.f;
        for (int i = 0; i < 8; ++i) sv += red[i * 256 + b * 4 + nl];
        ctb[b * DH + n0 + nl] = tanhf(sv);
      }
    }
    gg.sync();
    // ---- Phase G: gates + LSTM pointwise ----
    {
      const f32x4* wq1 = (const f32x4*)(WcL + j * 2052);
      const f32x4* wq2 = (const f32x4*)(WcL + j * 2052 + 1024);
      const f32x4* c0q = (const f32x4*)(ctb + b0 * DH);
      const f32x4* c1q = (const f32x4*)(ctb + b1 * DH);
      const f32x4* h0q = (const f32x4*)(hcur + b0 * DH);
      const f32x4* h1q = (const f32x4*)(hcur + b1 * DH);
      f32x4 v0 = {0, 0, 0, 0}, v1 = {0, 0, 0, 0};
      for (int q = 0; q < 256; ++q) {
        f32x4 wv = wq1[q];
        v0 += wv * c0q[q];
        v1 += wv * c1q[q];
      }
      for (int q = 0; q < 256; ++q) {
        f32x4 wv = wq2[q];
        v0 += wv * h0q[q];
        v1 += wv * h1q[q];
      }
      float a0 = sum4(v0) + __bfloat162float(Eg[((long)(ts * BB + b0)) * 4096 + rp]);
      float a1 = sum4(v1) + __bfloat162float(Eg[((long)(ts * BB + b1)) * 4096 + rp]);
      float gi0 = __shfl(a0, lbase + 0), gf0 = __shfl(a0, lbase + 1);
      float gg0 = __shfl(a0, lbase + 2), go0 = __shfl(a0, lbase + 3);
      float gi1 = __shfl(a1, lbase + 0), gf1 = __shfl(a1, lbase + 1);
      float gg1 = __shfl(a1, lbase + 2), go1 = __shfl(a1, lbase + 3);
      if ((t & 3) == 0) {
        float cn0 = sigm(gf0) * cd[b0 * DH + ju] + sigm(gi0) * tanhf(gg0);
        float hn0 = sigm(go0) * tanhf(cn0);
        cd[b0 * DH + ju] = cn0;
        hnew[b0 * DH + ju] = hn0;
        hTn[ju * 64 + b0] = hn0;
        A_bf[(long)ts * (BB * DH) + b0 * DH + ju] = __float2bfloat16(hn0);
        float cn1 = sigm(gf1) * cd[b1 * DH + ju] + sigm(gi1) * tanhf(gg1);
        float hn1 = sigm(go1) * tanhf(cn1);
        cd[b1 * DH + ju] = cn1;
        hnew[b1 * DH + ju] = hn1;
        hTn[ju * 64 + b1] = hn1;
        A_bf[(long)ts * (BB * DH) + b1 * DH + ju] = __float2bfloat16(hn1);
      }
    }
    { float* x = hcur; hcur = hnew; hnew = x; }
    { float* x = hTc; hTc = hTn; hTn = x; }
    gg.sync();
  }
}

// ---- bf16 MFMA generator GEMM (128x128 tile, m97 structure) ----
__global__ __launch_bounds__(256) void k_gen_mfma(
    const __hip_bfloat16* __restrict__ A, const __hip_bfloat16* __restrict__ Bw,
    const float* __restrict__ bias, float* __restrict__ C) {
  __shared__ __hip_bfloat16 As[128 * 32];
  __shared__ __hip_bfloat16 Bs[128 * 32];
  int tid = threadIdx.x;
  int lane = tid & 63, w = tid >> 6;
  long m0 = (long)blockIdx.y * 128, n0 = (long)blockIdx.x * 128;
  int srow = lane >> 2;
  int scol = (lane & 3) * 8;
  const __hip_bfloat16* gA0 = A + (m0 + w * 32 + srow) * GK + scol;
  const __hip_bfloat16* gA1 = gA0 + 16 * GK;
  const __hip_bfloat16* gB0 = Bw + (n0 + w * 32 + srow) * GK + scol;
  const __hip_bfloat16* gB1 = gB0 + 16 * GK;
  char* lA0 = (char*)As + w * 2048;
  char* lA1 = lA0 + 1024;
  char* lB0 = (char*)Bs + w * 2048;
  char* lB1 = lB0 + 1024;
  int wm = (w >> 1) * 64, wn = (w & 1) * 64;
  int fr = lane & 15;
  int kc = (lane >> 4) * 8;
  f32x4 acc[4][4] = {};
  for (int kt = 0; kt < GK / 32; ++kt) {
    int k0 = kt * 32;
    glds16(gA0 + k0, lA0);
    glds16(gA1 + k0, lA1);
    glds16(gB0 + k0, lB0);
    glds16(gB1 + k0, lB1);
    __syncthreads();
    bf16x8 a[4], b[4];
    for (int mi = 0; mi < 4; ++mi)
      a[mi] = *(const bf16x8*)(As + (wm + mi * 16 + fr) * 32 + kc);
    for (int ni = 0; ni < 4; ++ni)
      b[ni] = *(const bf16x8*)(Bs + (wn + ni * 16 + fr) * 32 + kc);
    for (int mi = 0; mi < 4; ++mi)
      for (int ni = 0; ni < 4; ++ni)
        acc[mi][ni] = __builtin_amdgcn_mfma_f32_16x16x32_bf16(a[mi], b[ni], acc[mi][ni], 0, 0, 0);
    __syncthreads();
  }
  for (int mi = 0; mi < 4; ++mi) {
    for (int ni = 0; ni < 4; ++ni) {
      int n = (int)n0 + wn + ni * 16 + (lane & 15);
      if (n >= GNRE) continue;
      float bv = bias[n];
      for (int r = 0; r < 4; ++r) {
        int m = (int)m0 + wm + mi * 16 + (lane >> 4) * 4 + r;
        if (m < GMRE) C[(long)m * TRGV + n] = acc[mi][ni][r] + bv;
      }
    }
  }
}

// in-place log-softmax over vocab for rows 64..3199 of out
__global__ __launch_bounds__(256) void k_logsoftmax(float* __restrict__ out) {
  int r = blockIdx.x;
  float* p = out + (long)(BB + r) * TRGV;
  int tid = threadIdx.x;
  __shared__ float red[256];
  float m = -1e30f;
  for (int i = tid; i < TRGV; i += 256) m = fmaxf(m, p[i]);
  red[tid] = m;
  __syncthreads();
  for (int s = 128; s > 0; s >>= 1) {
    if (tid < s) red[tid] = fmaxf(red[tid], red[tid + s]);
    __syncthreads();
  }
  m = red[0];
  __syncthreads();
  float sum = 0.f;
  for (int i = tid; i < TRGV; i += 256) sum += expf(p[i] - m);
  red[tid] = sum;
  __syncthreads();
  for (int s = 128; s > 0; s >>= 1) {
    if (tid < s) red[tid] += red[tid + s];
    __syncthreads();
  }
  float lse = m + logf(red[0]);
  for (int i = tid; i < TRGV; i += 256) p[i] -= lse;
}

extern "C" void kernel_launch(void* const* d_in, const int* in_sizes, int n_in,
                              void* d_out, int out_size, void* d_ws, size_t ws_size,
                              hipStream_t stream) {
  const int* src = (const int*)d_in[0];
  const int* trg = (const int*)d_in[1];
  const float* emb_en = (const float*)d_in[2];
  const float* emb_de = (const float*)d_in[3];
  const float* eWih_f = (const float*)d_in[4];
  const float* eWhh_f = (const float*)d_in[5];
  const float* eb_f = (const float*)d_in[6];
  const float* eWih_b = (const float*)d_in[7];
  const float* eWhh_b = (const float*)d_in[8];
  const float* eb_b = (const float*)d_in[9];
  const float* dWih = (const float*)d_in[10];
  const float* dWhh = (const float*)d_in[11];
  const float* db = (const float*)d_in[12];
  const float* Wgen = (const float*)d_in[13];
  const float* bgen = (const float*)d_in[14];
  const float* Wi = (const float*)d_in[15];
  const float* Wo = (const float*)d_in[16];
  float* out = (float*)d_out;

  float* base = (float*)d_ws;
  // ---- region RA (16,465,920 floats, time-multiplexed) ----
  // phase 1 (until encoder done):
  __hip_bfloat16* xsf = (__hip_bfloat16*)base;                    // 3200*640 bf16
  __hip_bfloat16* xsb = (__hip_bfloat16*)(base + 1024000);        // 3200*640
  __hip_bfloat16* Wihf2 = (__hip_bfloat16*)(base + 2048000);      // 2048*640
  __hip_bfloat16* Wihb2 = (__hip_bfloat16*)(base + 2703360);      // 2048*640
  float* xW_f = base + 3358720;                                   // 3200*2048
  float* xW_b = base + 9912320;                                   // 3200*2048
  // phase 2 (after encoder):
  __hip_bfloat16* hs2 = (__hip_bfloat16*)base;                    // 3200*2048
  __hip_bfloat16* Wi2 = (__hip_bfloat16*)(base + 3276800);        // 1024*2048
  __hip_bfloat16* Wo12 = (__hip_bfloat16*)(base + 4325376);       // 1024*2048
  __hip_bfloat16* eg2 = (__hip_bfloat16*)(base + 5373952);        // 3200*640
  __hip_bfloat16* Wce2 = (__hip_bfloat16*)(base + 6397952);       // 4096*640
  __hip_bfloat16* E_g = (__hip_bfloat16*)(base + 7708672);        // 3136*4096 (lives thru decoder)
  // phase 3 (after decoder):
  __hip_bfloat16* Wgen_bf = (__hip_bfloat16*)base;                // 23296*1024
  // ---- region RB (persistent) ----
  float* p = base + 16465920;
  float* x_enc = p; p += SS * BB * EE;                // 960,000
  float* hs = p; p += (long)SS * BB * DH;             // 3,276,800
  float* G = p; p += (long)SS * BB * DH;              // 3,276,800
  float* HsWo1 = p; p += (long)SS * BB * DH;          // 3,276,800
  __hip_bfloat16* A_bf = (__hip_bfloat16*)p; p += (GMP * GK) / 2;  // 1,638,400
  float* dbp = p; p += 4096;
  float* attw = p; p += SS * BB;
  float* hd0 = p; p += BB * DH;
  float* hd1 = p; p += BB * DH;
  float* hT0 = p; p += BB * DH;
  float* hT1 = p; p += BB * DH;
  float* cd = p; p += BB * DH;
  float* ctb = p; p += BB * DH;
  float* hA = p; p += BB * EH;
  float* hB = p; p += BB * EH;
  float* hA2 = p; p += BB * EH;
  float* hB2 = p; p += BB * EH;
  float* cf = p; p += BB * EH;
  float* cb = p; p += BB * EH;

  dim3 b256(256);

  // ---- setup ----
  k_embed<<<dim3((SS * BB * EE + 255) / 256), b256, 0, stream>>>(src, emb_en, x_enc);
  k_zero<<<dim3((6 * BB * EH + 255) / 256), b256, 0, stream>>>(hA, 6 * BB * EH);
  k_zero<<<dim3((int)(((long)BB * TRGV + 255) / 256)), b256, 0, stream>>>(out, (long)BB * TRGV);
  k_zero_bf<<<dim3(((GMP - GMRE) * GK + 255) / 256), b256, 0, stream>>>(
      A_bf + (long)GMRE * GK, (long)(GMP - GMRE) * GK);
  k_dbperm<<<dim3(16), b256, 0, stream>>>(db, dbp);

  // ---- encoder input: splits + split-MFMA GEMMs ----
  k_split_pad<<<dim3((3200 * 320 + 255) / 256), b256, 0, stream>>>(
      x_enc, EE, 0, EE, 320, 3200, 3200, 0, xsf);
  k_split_pad<<<dim3((3200 * 320 + 255) / 256), b256, 0, stream>>>(
      x_enc, EE, 0, EE, 320, 3200, 3200, 1, xsb);
  k_split_pad<<<dim3((2048 * 320 + 255) / 256), b256, 0, stream>>>(
      eWih_f, EE, 0, EE, 320, 2048, 2048, 0, Wihf2);
  k_split_pad<<<dim3((2048 * 320 + 255) / 256), b256, 0, stream>>>(
      eWih_b, EE, 0, EE, 320, 2048, 2048, 0, Wihb2);
  k_gsplit<0><<<dim3(16, 25), b256, 0, stream>>>(xsf, Wihf2, eb_f, xW_f, 3200, 2048, 2048, 320);
  k_gsplit<0><<<dim3(16, 25), b256, 0, stream>>>(xsb, Wihb2, eb_b, xW_b, 3200, 2048, 2048, 320);

  // ---- persistent encoder ----
  {
    void* args[] = {(void*)&xW_f, (void*)&xW_b, (void*)&eWhh_f, (void*)&eWhh_b,
                    (void*)&hs, (void*)&hA, (void*)&hB, (void*)&hA2, (void*)&hB2,
                    (void*)&cf, (void*)&cb, (void*)&hd0, (void*)&hT0, (void*)&cd};
    hipLaunchCooperativeKernel((const void*)persist_enc, dim3(256), dim3(512),
                               args, 0, stream);
  }

  // ---- decoder-loop hoists: G = hs@Wi (TRANSPOSED split!), HsWo1, E_gates ----
  k_split_pad<<<dim3((int)((3200L * 1024 + 255) / 256)), b256, 0, stream>>>(
      hs, DH, 0, DH, 1024, 3200, 3200, 0, hs2);
  k_split_pad<<<dim3((int)((1024L * 1024 + 255) / 256)), b256, 0, stream>>>(
      Wi, DH, 0, DH, 1024, 1024, 1024, 3, Wi2);   // mode 3: Wi2[r][k] = Wi[k][r]
  k_split_pad<<<dim3((int)((1024L * 1024 + 255) / 256)), b256, 0, stream>>>(
      Wo, 2 * DH, 0, DH, 1024, 1024, 1024, 0, Wo12);
  k_embgather_split<<<dim3((int)((3200L * 320 + 255) / 256)), b256, 0, stream>>>(
      trg, emb_de, eg2);
  k_split_pad<<<dim3((int)((4096L * 320 + 255) / 256)), b256, 0, stream>>>(
      dWih, 1324, 1024, EE, 320, 4096, 4096, 2, Wce2);
  k_gsplit<0><<<dim3(8, 25), b256, 0, stream>>>(hs2, Wi2, (const float*)nullptr, G, 3200, 1024, 1024, 1024);
  k_gsplit<0><<<dim3(8, 25), b256, 0, stream>>>(hs2, Wo12, (const float*)nullptr, HsWo1, 3200, 1024, 1024, 1024);
  k_gsplit<1><<<dim3(32, 25), b256, 0, stream>>>(eg2, Wce2, dbp, E_g, 3136, 4096, 4096, 320);

  // ---- persistent decoder (weights pinned in LDS) ----
  {
    void* args[] = {(void*)&G, (void*)&HsWo1, (void*)&Wo, (void*)&dWih, (void*)&dWhh,
                    (void*)&E_g, (void*)&hd0, (void*)&hd1, (void*)&hT0, (void*)&hT1,
                    (void*)&cd, (void*)&attw, (void*)&ctb, (void*)&A_bf};
    hipLaunchCooperativeKernel((const void*)persist_dec, dim3(256), dim3(512),
                               args, 0, stream);
  }

  // ---- generator: Wgen -> bf16 (RA free now), MFMA GEMM + log-softmax ----
  k_tobf16_pad<<<dim3((int)(((long)GNP * GK + 255) / 256)), b256, 0, stream>>>(
      Wgen, Wgen_bf, GNRE, GNP, GK);
  k_gen_mfma<<<dim3(GNP / 128, GMP / 128), b256, 0, stream>>>(
      A_bf, Wgen_bf, bgen, out + (long)BB * TRGV);
  k_logsoftmax<<<dim3((TT - 1) * BB), b256, 0, stream>>>(out);
}

// Round 8
// 9770.464 us; speedup vs baseline: 2.5270x; 1.2518x over previous
//
#include <hip/hip_runtime.h>
#include <hip/hip_bf16.h>

#define SS 50
#define TT 50
#define BB 64
#define TRGV 23262
#define EE 300
#define EH 512
#define DH 1024

// generator GEMM geometry (bf16 MFMA)
#define GMRE 3136
#define GMP 3200
#define GK 1024
#define GNRE TRGV
#define GNP 23296

typedef short bf16x8 __attribute__((ext_vector_type(8)));
typedef float f32x4 __attribute__((ext_vector_type(4)));

__device__ __forceinline__ void glds16(const void* g, void* l) {
  __builtin_amdgcn_global_load_lds(
      (const __attribute__((address_space(1))) void*)g,
      (__attribute__((address_space(3))) void*)l, 16, 0, 0);
}

__device__ __forceinline__ float sigm(float x) { return 1.f / (1.f + expf(-x)); }
__device__ __forceinline__ float sum4(f32x4 v) { return v[0] + v[1] + v[2] + v[3]; }

__device__ __forceinline__ void split2(float x, __hip_bfloat16& hi, __hip_bfloat16& lo) {
  hi = __float2bfloat16(x);
  lo = __float2bfloat16(x - __bfloat162float(hi));
}

// ---- custom agent-scope grid barrier (cheaper than cg::grid.sync) ----
// cnt/gen in device memory (zeroed each kernel_launch). Release-sequence via
// ACQ_REL RMWs; last arrival resets cnt BEFORE release-publishing gen (safe:
// spinners acquire gen-new, so their next RMW on cnt observes the reset).
__device__ __forceinline__ void gbar(unsigned* cnt, unsigned* gen, unsigned nblk) {
  __syncthreads();
  if (threadIdx.x == 0) {
    unsigned g = __hip_atomic_load(gen, __ATOMIC_RELAXED, __HIP_MEMORY_SCOPE_AGENT);
    unsigned a = __hip_atomic_fetch_add(cnt, 1u, __ATOMIC_ACQ_REL, __HIP_MEMORY_SCOPE_AGENT);
    if (a == nblk - 1u) {
      __hip_atomic_store(cnt, 0u, __ATOMIC_RELAXED, __HIP_MEMORY_SCOPE_AGENT);
      __hip_atomic_store(gen, g + 1u, __ATOMIC_RELEASE, __HIP_MEMORY_SCOPE_AGENT);
    } else {
      while (__hip_atomic_load(gen, __ATOMIC_RELAXED, __HIP_MEMORY_SCOPE_AGENT) == g)
        __builtin_amdgcn_s_sleep(2);
      (void)__hip_atomic_load(gen, __ATOMIC_ACQUIRE, __HIP_MEMORY_SCOPE_AGENT);
    }
  }
  __syncthreads();
}

__global__ void k_zero(float* __restrict__ p, long n) {
  long i = (long)blockIdx.x * 256 + threadIdx.x;
  if (i < n) p[i] = 0.f;
}
__global__ void k_zero_bf(__hip_bfloat16* __restrict__ p, long n) {
  long i = (long)blockIdx.x * 256 + threadIdx.x;
  if (i < n) p[i] = __float2bfloat16(0.f);
}

__global__ void k_embed(const int* __restrict__ src, const float* __restrict__ emb,
                        float* __restrict__ x) {
  int id = blockIdx.x * 256 + threadIdx.x;
  if (id >= SS * BB * EE) return;
  int sb = id / EE, e = id % EE;
  x[id] = emb[(long)src[sb] * EE + e];
}

__global__ void k_dbperm(const float* __restrict__ db, float* __restrict__ dbp) {
  int id = blockIdx.x * 256 + threadIdx.x;
  if (id >= 4096) return;
  int u = id >> 2, g = id & 3;
  dbp[id] = db[g * 1024 + u];
}

// fp32 [rows][ld] (+col_off) -> [rows_pad][2*Kpad] bf16 hi|lo, zero pad.
// mode 0: src=r ; 1: seq-reverse per 64 ; 2: gate-perm rp=4u+g <- g*1024+u ; 3: transpose
__global__ void k_split_pad(const float* __restrict__ in, int ld_in, int col_off,
                            int Kreal, int Kpad, int rows_real, long rows_pad,
                            int mode, __hip_bfloat16* __restrict__ out) {
  long id = (long)blockIdx.x * 256 + threadIdx.x;
  if (id >= rows_pad * Kpad) return;
  long r = id / Kpad;
  int k = id % Kpad;
  float v = 0.f;
  if (r < rows_real && k < Kreal) {
    if (mode == 3) {
      v = in[(long)k * ld_in + col_off + r];
    } else {
      long sr = r;
      if (mode == 1) sr = ((49 - (r >> 6)) << 6) + (r & 63);
      else if (mode == 2) sr = (long)(r & 3) * 1024 + (r >> 2);
      v = in[sr * ld_in + col_off + k];
    }
  }
  __hip_bfloat16 hi, lo;
  split2(v, hi, lo);
  out[r * 2 * Kpad + k] = hi;
  out[r * 2 * Kpad + Kpad + k] = lo;
}

// gather emb_de[trg[t,b]] -> split [3200][2*320]
__global__ void k_embgather_split(const int* __restrict__ trg, const float* __restrict__ emb,
                                  __hip_bfloat16* __restrict__ out) {
  long id = (long)blockIdx.x * 256 + threadIdx.x;
  if (id >= 3200L * 320) return;
  long r = id / 320;
  int k = id % 320;
  int t = r >> 6, b = r & 63;
  float v = 0.f;
  if (t < TT - 1 && k < EE) v = emb[(long)trg[t * BB + b] * EE + k];
  __hip_bfloat16 hi, lo;
  split2(v, hi, lo);
  out[r * 640 + k] = hi;
  out[r * 640 + 320 + k] = lo;
}

// plain bf16 with zero row padding (generator weight)
__global__ void k_tobf16_pad(const float* __restrict__ W, __hip_bfloat16* __restrict__ Wb,
                             long nrow_real, long nrow_pad, int K) {
  long id = (long)blockIdx.x * 256 + threadIdx.x;
  if (id >= nrow_pad * K) return;
  long r = id / K;
  Wb[id] = __float2bfloat16(r < nrow_real ? W[id] : 0.f);
}

// repack HsWo1 [3200][1024] -> HsWo1T [256 colblk][3200 row][4]
__global__ void k_repackT(const float* __restrict__ in, float* __restrict__ out) {
  long id = (long)blockIdx.x * 256 + threadIdx.x;
  if (id >= 3200L * 1024) return;
  long r = id >> 10;
  int n = id & 1023;
  out[((long)(n >> 2) * 3200 + r) * 4 + (n & 3)] = in[id];
}

// ---- generic split-bf16 MFMA GEMM (3-pass: AhWh + AlWh + AhWl), 128x128 tile ----
template<int OUTBF>
__global__ __launch_bounds__(256) void k_gsplit(
    const __hip_bfloat16* __restrict__ A2, const __hip_bfloat16* __restrict__ W2,
    const float* __restrict__ bias, void* __restrict__ Cout,
    int Mreal, int Nreal, int ldc, int Kpad) {
  __shared__ __hip_bfloat16 As[128 * 32];
  __shared__ __hip_bfloat16 Bs[128 * 32];
  int tid = threadIdx.x, lane = tid & 63, w = tid >> 6;
  long m0 = (long)blockIdx.y * 128, n0 = (long)blockIdx.x * 128;
  int lda2 = 2 * Kpad;
  int srow = lane >> 2;
  int scol = (lane & 3) * 8;
  char* lA0 = (char*)As + w * 2048;
  char* lA1 = lA0 + 1024;
  char* lB0 = (char*)Bs + w * 2048;
  char* lB1 = lB0 + 1024;
  int wm = (w >> 1) * 64, wn = (w & 1) * 64;
  int fr = lane & 15;
  int kc = (lane >> 4) * 8;
  f32x4 acc[4][4] = {};

  for (int seg = 0; seg < 3; ++seg) {
    const __hip_bfloat16* Ab = A2 + (seg == 1 ? Kpad : 0);
    const __hip_bfloat16* Wb = W2 + (seg == 2 ? Kpad : 0);
    const __hip_bfloat16* gA0 = Ab + (m0 + w * 32 + srow) * (long)lda2 + scol;
    const __hip_bfloat16* gA1 = gA0 + 16L * lda2;
    const __hip_bfloat16* gB0 = Wb + (n0 + w * 32 + srow) * (long)lda2 + scol;
    const __hip_bfloat16* gB1 = gB0 + 16L * lda2;
    for (int kt = 0; kt < Kpad / 32; ++kt) {
      int k0 = kt * 32;
      glds16(gA0 + k0, lA0);
      glds16(gA1 + k0, lA1);
      glds16(gB0 + k0, lB0);
      glds16(gB1 + k0, lB1);
      __syncthreads();
      bf16x8 a[4], b[4];
      for (int mi = 0; mi < 4; ++mi)
        a[mi] = *(const bf16x8*)(As + (wm + mi * 16 + fr) * 32 + kc);
      for (int ni = 0; ni < 4; ++ni)
        b[ni] = *(const bf16x8*)(Bs + (wn + ni * 16 + fr) * 32 + kc);
      for (int mi = 0; mi < 4; ++mi)
        for (int ni = 0; ni < 4; ++ni)
          acc[mi][ni] = __builtin_amdgcn_mfma_f32_16x16x32_bf16(a[mi], b[ni], acc[mi][ni], 0, 0, 0);
      __syncthreads();
    }
  }

  for (int mi = 0; mi < 4; ++mi) {
    for (int ni = 0; ni < 4; ++ni) {
      int n = (int)n0 + wn + ni * 16 + (lane & 15);
      if (n >= Nreal) continue;
      float bv = bias ? bias[n] : 0.f;
      for (int r = 0; r < 4; ++r) {
        int m = (int)m0 + wm + mi * 16 + (lane >> 4) * 4 + r;
        if (m >= Mreal) continue;
        float v = acc[mi][ni][r] + bv;
        if (OUTBF) ((__hip_bfloat16*)Cout)[(long)m * ldc + n] = __float2bfloat16(v);
        else ((float*)Cout)[(long)m * ldc + n] = v;
      }
    }
  }
}

// ---- persistent encoder: Whh in LDS, 1 custom barrier/step ----
__global__ __launch_bounds__(512) void persist_enc(
    const float* __restrict__ xW_f, const float* __restrict__ xW_b,
    const float* __restrict__ Whf, const float* __restrict__ Whb,
    float* __restrict__ hs, float* hA, float* hB, float* hA2, float* hB2,
    float* __restrict__ cf, float* __restrict__ cb,
    float* __restrict__ hd0, float* __restrict__ hT0, float* __restrict__ cdD,
    unsigned* __restrict__ bar) {
  __shared__ float WL[16 * 516];
  int t = threadIdx.x;
  int blk = blockIdx.x;
  int dir = blk >> 7, bl = blk & 127;
  const float* Whh = dir ? Whb : Whf;
  const float* xWb0 = dir ? xW_b : xW_f;
  float* c = dir ? cb : cf;
  float* hp = dir ? hA2 : hA;
  float* hn = dir ? hB2 : hB;
  unsigned* cnt = bar;
  unsigned* gen = bar + 16;

  for (int idx = t; idx < 16 * 512; idx += 512) {
    int r = idx >> 9, k = idx & 511;
    int srcrow = (r & 3) * 512 + (bl * 4 + (r >> 2));
    WL[r * 516 + k] = Whh[(long)srcrow * 512 + k];
  }
  __syncthreads();

  int j = t & 15;
  int b0 = t >> 4, b1 = b0 + 32;
  int g = j & 3;
  int ju = bl * 4 + (j >> 2);
  int lbase = (t & 63) & ~3;
  const f32x4* wq = (const f32x4*)(WL + j * 516);

  for (int s = 0; s < SS; ++s) {
    const f32x4* h0q = (const f32x4*)(hp + b0 * 512);
    const f32x4* h1q = (const f32x4*)(hp + b1 * 512);
    f32x4 v0 = {0, 0, 0, 0}, v1 = {0, 0, 0, 0};
    for (int q = 0; q < 128; ++q) {
      f32x4 wv = wq[q];
      v0 += wv * h0q[q];
      v1 += wv * h1q[q];
    }
    const float* xW = xWb0 + (long)(s * BB) * 2048;
    float a0 = sum4(v0) + xW[b0 * 2048 + g * 512 + ju];
    float a1 = sum4(v1) + xW[b1 * 2048 + g * 512 + ju];
    float gi0 = __shfl(a0, lbase + 0), gf0 = __shfl(a0, lbase + 1);
    float gg0 = __shfl(a0, lbase + 2), go0 = __shfl(a0, lbase + 3);
    float gi1 = __shfl(a1, lbase + 0), gf1 = __shfl(a1, lbase + 1);
    float gg1 = __shfl(a1, lbase + 2), go1 = __shfl(a1, lbase + 3);
    if ((t & 3) == 0) {
      int hscol = dir ? (512 + ju) : ju;
      int srow = dir ? (SS - 1 - s) : s;
      long hsrow0 = (long)(srow * BB + b0) * DH + hscol;
      long hsrow1 = (long)(srow * BB + b1) * DH + hscol;
      float cn0 = sigm(gf0) * c[b0 * 512 + ju] + sigm(gi0) * tanhf(gg0);
      float hn0 = sigm(go0) * tanhf(cn0);
      c[b0 * 512 + ju] = cn0;
      hn[b0 * 512 + ju] = hn0;
      hs[hsrow0] = hn0;
      float cn1 = sigm(gf1) * c[b1 * 512 + ju] + sigm(gi1) * tanhf(gg1);
      float hn1 = sigm(go1) * tanhf(cn1);
      c[b1 * 512 + ju] = cn1;
      hn[b1 * 512 + ju] = hn1;
      hs[hsrow1] = hn1;
    }
    float* tmp = hp; hp = hn; hn = tmp;
    gbar(cnt, gen, 256);
  }
  int gid = blk * 512 + t;
  if (gid < 65536) {
    int d2 = gid >> 15, b = (gid >> 9) & 63, j2 = gid & 511;
    float hv = (d2 ? hA2 : hA)[b * 512 + j2];
    float cv = (d2 ? cb : cf)[b * 512 + j2];
    hd0[gid] = hv;
    cdD[gid] = cv;
    int bp = gid >> 10, jp = gid & 1023;
    hT0[jp * 64 + bp] = hv;
  }
}

// ---- persistent decoder: Wc13 + Wo2 pinned in LDS, 3 custom barriers/step ----
__global__ __launch_bounds__(512) void persist_dec(
    const float* __restrict__ G, const float* __restrict__ HsWo1T,
    const float* __restrict__ Wo, const float* __restrict__ dWih,
    const float* __restrict__ dWhh, const __hip_bfloat16* __restrict__ Eg,
    float* hd0, float* hd1, float* hT0, float* hT1,
    float* __restrict__ cd, float* __restrict__ attw, float* __restrict__ ctb,
    __hip_bfloat16* __restrict__ A_bf, unsigned* __restrict__ bar) {
  __shared__ float WcL[16 * 2052];
  __shared__ float WoL[4 * 1028];
  __shared__ float red[2048];
  int t = threadIdx.x;
  int blk = blockIdx.x;
  int w = t >> 6, lane = t & 63;
  unsigned* cnt = bar;
  unsigned* gen = bar + 16;

  for (int idx = t; idx < 16 * 2048; idx += 512) {
    int r = idx >> 11, k = idx & 2047;
    int rp2 = blk * 16 + r;
    long srcrow = (long)(rp2 & 3) * 1024 + (rp2 >> 2);
    float v = (k < 1024) ? dWih[srcrow * 1324 + k] : dWhh[srcrow * 1024 + (k - 1024)];
    WcL[r * 2052 + k] = v;
  }
  for (int idx = t; idx < 4 * 1024; idx += 512) {
    int r = idx >> 10, k = idx & 1023;
    WoL[r * 1028 + k] = Wo[(long)(blk * 4 + r) * 2048 + 1024 + k];
  }
  __syncthreads();

  float* hcur = hd0; float* hnew = hd1;
  float* hTc = hT0;  float* hTn = hT1;
  int j = t & 15;
  int b0 = t >> 4, b1 = b0 + 32;
  int rp = blk * 16 + j;
  int ju = blk * 4 + (j >> 2);
  int lbase = (t & 63) & ~3;
  const f32x4* hw = (const f32x4*)(HsWo1T + (long)blk * 3200 * 4);

  for (int ts = 0; ts < TT - 1; ++ts) {
    // ---- Phase S: scores[s,b] = h[b,:]·G[s,b,:], softmax over b ----
    if (blk < SS) {
      int s = blk;
      const f32x4* gq = (const f32x4*)(G + ((long)(s * BB + lane)) * DH + w * 128);
      const f32x4* hq = (const f32x4*)(hcur + lane * DH + w * 128);
      f32x4 a4 = {0, 0, 0, 0};
      for (int q = 0; q < 32; ++q) a4 += gq[q] * hq[q];
      red[w * 64 + lane] = sum4(a4);
      __syncthreads();
      if (w == 0) {
        float sc = 0.f;
        for (int i = 0; i < 8; ++i) sc += red[i * 64 + lane];
        float m = sc;
        for (int o = 32; o > 0; o >>= 1) m = fmaxf(m, __shfl_xor(m, o));
        float e = expf(sc - m);
        float su = e;
        for (int o = 32; o > 0; o >>= 1) su += __shfl_xor(su, o);
        attw[s * BB + lane] = e / su;
      }
    }
    gbar(cnt, gen, 256);
    // ---- Phase TC: ct[b, blk*4+nl] = tanh( sum_s a*HsWo1T + h@Wo2 ) ----
    {
      int n0 = blk * 4;
      f32x4 z = {0, 0, 0, 0};
      for (int s = w; s < SS; s += 8) {
        float aw = attw[s * BB + lane];
        f32x4 hv = hw[s * 64 + lane];
        z += aw * hv;
      }
      for (int k = w * 128; k < w * 128 + 128; ++k) {
        float hb = hTc[k * 64 + lane];
        f32x4 wv = {WoL[0 * 1028 + k], WoL[1 * 1028 + k], WoL[2 * 1028 + k], WoL[3 * 1028 + k]};
        z += hb * wv;
      }
      red[w * 256 + lane * 4 + 0] = z[0];
      red[w * 256 + lane * 4 + 1] = z[1];
      red[w * 256 + lane * 4 + 2] = z[2];
      red[w * 256 + lane * 4 + 3] = z[3];
      __syncthreads();
      if (t < 256) {
        int b = t >> 2, nl = t & 3;
        float sv = 0.f;
        for (int i = 0; i < 8; ++i) sv += red[i * 256 + b * 4 + nl];
        ctb[b * DH + n0 + nl] = tanhf(sv);
      }
    }
    gbar(cnt, gen, 256);
    // ---- Phase G: gates + LSTM pointwise ----
    {
      const f32x4* wq1 = (const f32x4*)(WcL + j * 2052);
      const f32x4* wq2 = (const f32x4*)(WcL + j * 2052 + 1024);
      const f32x4* c0q = (const f32x4*)(ctb + b0 * DH);
      const f32x4* c1q = (const f32x4*)(ctb + b1 * DH);
      const f32x4* h0q = (const f32x4*)(hcur + b0 * DH);
      const f32x4* h1q = (const f32x4*)(hcur + b1 * DH);
      f32x4 v0 = {0, 0, 0, 0}, v1 = {0, 0, 0, 0};
      for (int q = 0; q < 256; ++q) {
        f32x4 wv = wq1[q];
        v0 += wv * c0q[q];
        v1 += wv * c1q[q];
      }
      for (int q = 0; q < 256; ++q) {
        f32x4 wv = wq2[q];
        v0 += wv * h0q[q];
        v1 += wv * h1q[q];
      }
      float a0 = sum4(v0) + __bfloat162float(Eg[((long)(ts * BB + b0)) * 4096 + rp]);
      float a1 = sum4(v1) + __bfloat162float(Eg[((long)(ts * BB + b1)) * 4096 + rp]);
      float gi0 = __shfl(a0, lbase + 0), gf0 = __shfl(a0, lbase + 1);
      float gg0 = __shfl(a0, lbase + 2), go0 = __shfl(a0, lbase + 3);
      float gi1 = __shfl(a1, lbase + 0), gf1 = __shfl(a1, lbase + 1);
      float gg1 = __shfl(a1, lbase + 2), go1 = __shfl(a1, lbase + 3);
      if ((t & 3) == 0) {
        float cn0 = sigm(gf0) * cd[b0 * DH + ju] + sigm(gi0) * tanhf(gg0);
        float hn0 = sigm(go0) * tanhf(cn0);
        cd[b0 * DH + ju] = cn0;
        hnew[b0 * DH + ju] = hn0;
        hTn[ju * 64 + b0] = hn0;
        A_bf[(long)ts * (BB * DH) + b0 * DH + ju] = __float2bfloat16(hn0);
        float cn1 = sigm(gf1) * cd[b1 * DH + ju] + sigm(gi1) * tanhf(gg1);
        float hn1 = sigm(go1) * tanhf(cn1);
        cd[b1 * DH + ju] = cn1;
        hnew[b1 * DH + ju] = hn1;
        hTn[ju * 64 + b1] = hn1;
        A_bf[(long)ts * (BB * DH) + b1 * DH + ju] = __float2bfloat16(hn1);
      }
    }
    { float* x = hcur; hcur = hnew; hnew = x; }
    { float* x = hTc; hTc = hTn; hTn = x; }
    gbar(cnt, gen, 256);
  }
}

// ---- bf16 MFMA generator GEMM (128x128 tile, m97 structure) ----
__global__ __launch_bounds__(256) void k_gen_mfma(
    const __hip_bfloat16* __restrict__ A, const __hip_bfloat16* __restrict__ Bw,
    const float* __restrict__ bias, float* __restrict__ C) {
  __shared__ __hip_bfloat16 As[128 * 32];
  __shared__ __hip_bfloat16 Bs[128 * 32];
  int tid = threadIdx.x;
  int lane = tid & 63, w = tid >> 6;
  long m0 = (long)blockIdx.y * 128, n0 = (long)blockIdx.x * 128;
  int srow = lane >> 2;
  int scol = (lane & 3) * 8;
  const __hip_bfloat16* gA0 = A + (m0 + w * 32 + srow) * GK + scol;
  const __hip_bfloat16* gA1 = gA0 + 16 * GK;
  const __hip_bfloat16* gB0 = Bw + (n0 + w * 32 + srow) * GK + scol;
  const __hip_bfloat16* gB1 = gB0 + 16 * GK;
  char* lA0 = (char*)As + w * 2048;
  char* lA1 = lA0 + 1024;
  char* lB0 = (char*)Bs + w * 2048;
  char* lB1 = lB0 + 1024;
  int wm = (w >> 1) * 64, wn = (w & 1) * 64;
  int fr = lane & 15;
  int kc = (lane >> 4) * 8;
  f32x4 acc[4][4] = {};
  for (int kt = 0; kt < GK / 32; ++kt) {
    int k0 = kt * 32;
    glds16(gA0 + k0, lA0);
    glds16(gA1 + k0, lA1);
    glds16(gB0 + k0, lB0);
    glds16(gB1 + k0, lB1);
    __syncthreads();
    bf16x8 a[4], b[4];
    for (int mi = 0; mi < 4; ++mi)
      a[mi] = *(const bf16x8*)(As + (wm + mi * 16 + fr) * 32 + kc);
    for (int ni = 0; ni < 4; ++ni)
      b[ni] = *(const bf16x8*)(Bs + (wn + ni * 16 + fr) * 32 + kc);
    for (int mi = 0; mi < 4; ++mi)
      for (int ni = 0; ni < 4; ++ni)
        acc[mi][ni] = __builtin_amdgcn_mfma_f32_16x16x32_bf16(a[mi], b[ni], acc[mi][ni], 0, 0, 0);
    __syncthreads();
  }
  for (int mi = 0; mi < 4; ++mi) {
    for (int ni = 0; ni < 4; ++ni) {
      int n = (int)n0 + wn + ni * 16 + (lane & 15);
      if (n >= GNRE) continue;
      float bv = bias[n];
      for (int r = 0; r < 4; ++r) {
        int m = (int)m0 + wm + mi * 16 + (lane >> 4) * 4 + r;
        if (m < GMRE) C[(long)m * TRGV + n] = acc[mi][ni][r] + bv;
      }
    }
  }
}

// in-place log-softmax over vocab for rows 64..3199 of out
__global__ __launch_bounds__(256) void k_logsoftmax(float* __restrict__ out) {
  int r = blockIdx.x;
  float* p = out + (long)(BB + r) * TRGV;
  int tid = threadIdx.x;
  __shared__ float red[256];
  float m = -1e30f;
  for (int i = tid; i < TRGV; i += 256) m = fmaxf(m, p[i]);
  red[tid] = m;
  __syncthreads();
  for (int s = 128; s > 0; s >>= 1) {
    if (tid < s) red[tid] = fmaxf(red[tid], red[tid + s]);
    __syncthreads();
  }
  m = red[0];
  __syncthreads();
  float sum = 0.f;
  for (int i = tid; i < TRGV; i += 256) sum += expf(p[i] - m);
  red[tid] = sum;
  __syncthreads();
  for (int s = 128; s > 0; s >>= 1) {
    if (tid < s) red[tid] += red[tid + s];
    __syncthreads();
  }
  float lse = m + logf(red[0]);
  for (int i = tid; i < TRGV; i += 256) p[i] -= lse;
}

extern "C" void kernel_launch(void* const* d_in, const int* in_sizes, int n_in,
                              void* d_out, int out_size, void* d_ws, size_t ws_size,
                              hipStream_t stream) {
  const int* src = (const int*)d_in[0];
  const int* trg = (const int*)d_in[1];
  const float* emb_en = (const float*)d_in[2];
  const float* emb_de = (const float*)d_in[3];
  const float* eWih_f = (const float*)d_in[4];
  const float* eWhh_f = (const float*)d_in[5];
  const float* eb_f = (const float*)d_in[6];
  const float* eWih_b = (const float*)d_in[7];
  const float* eWhh_b = (const float*)d_in[8];
  const float* eb_b = (const float*)d_in[9];
  const float* dWih = (const float*)d_in[10];
  const float* dWhh = (const float*)d_in[11];
  const float* db = (const float*)d_in[12];
  const float* Wgen = (const float*)d_in[13];
  const float* bgen = (const float*)d_in[14];
  const float* Wi = (const float*)d_in[15];
  const float* Wo = (const float*)d_in[16];
  float* out = (float*)d_out;

  float* base = (float*)d_ws;
  // ---- region RA (16,465,920 floats, time-multiplexed) ----
  __hip_bfloat16* xsf = (__hip_bfloat16*)base;
  __hip_bfloat16* xsb = (__hip_bfloat16*)(base + 1024000);
  __hip_bfloat16* Wihf2 = (__hip_bfloat16*)(base + 2048000);
  __hip_bfloat16* Wihb2 = (__hip_bfloat16*)(base + 2703360);
  float* xW_f = base + 3358720;
  float* xW_b = base + 9912320;
  __hip_bfloat16* hs2 = (__hip_bfloat16*)base;
  __hip_bfloat16* Wi2 = (__hip_bfloat16*)(base + 3276800);
  __hip_bfloat16* Wo12 = (__hip_bfloat16*)(base + 4325376);
  __hip_bfloat16* eg2 = (__hip_bfloat16*)(base + 5373952);
  __hip_bfloat16* Wce2 = (__hip_bfloat16*)(base + 6397952);
  __hip_bfloat16* E_g = (__hip_bfloat16*)(base + 7708672);
  __hip_bfloat16* Wgen_bf = (__hip_bfloat16*)base;   // phase 3
  // ---- region RB (persistent) ----
  float* p = base + 16465920;
  float* x_enc = p; p += SS * BB * EE;
  float* hs = p; p += (long)SS * BB * DH;
  float* G = p; p += (long)SS * BB * DH;
  float* HsWo1 = p; p += (long)SS * BB * DH;
  float* HsWo1T = p; p += (long)SS * BB * DH;
  __hip_bfloat16* A_bf = (__hip_bfloat16*)p; p += (GMP * GK) / 2;
  float* dbp = p; p += 4096;
  float* attw = p; p += SS * BB;
  float* hd0 = p; p += BB * DH;
  float* hd1 = p; p += BB * DH;
  float* hT0 = p; p += BB * DH;
  float* hT1 = p; p += BB * DH;
  float* cd = p; p += BB * DH;
  float* ctb = p; p += BB * DH;
  float* hA = p; p += BB * EH;
  float* hB = p; p += BB * EH;
  float* hA2 = p; p += BB * EH;
  float* hB2 = p; p += BB * EH;
  float* cf = p; p += BB * EH;
  float* cb = p; p += BB * EH;
  unsigned* bar = (unsigned*)p; p += 64;   // barrier cnt@0, gen@16

  dim3 b256(256);

  // ---- setup ----
  k_embed<<<dim3((SS * BB * EE + 255) / 256), b256, 0, stream>>>(src, emb_en, x_enc);
  k_zero<<<dim3((6 * BB * EH + 255) / 256), b256, 0, stream>>>(hA, 6 * BB * EH);
  k_zero<<<dim3(1), b256, 0, stream>>>((float*)bar, 64);
  k_zero<<<dim3((int)(((long)BB * TRGV + 255) / 256)), b256, 0, stream>>>(out, (long)BB * TRGV);
  k_zero_bf<<<dim3(((GMP - GMRE) * GK + 255) / 256), b256, 0, stream>>>(
      A_bf + (long)GMRE * GK, (long)(GMP - GMRE) * GK);
  k_dbperm<<<dim3(16), b256, 0, stream>>>(db, dbp);

  // ---- encoder input: splits + split-MFMA GEMMs ----
  k_split_pad<<<dim3((3200 * 320 + 255) / 256), b256, 0, stream>>>(
      x_enc, EE, 0, EE, 320, 3200, 3200, 0, xsf);
  k_split_pad<<<dim3((3200 * 320 + 255) / 256), b256, 0, stream>>>(
      x_enc, EE, 0, EE, 320, 3200, 3200, 1, xsb);
  k_split_pad<<<dim3((2048 * 320 + 255) / 256), b256, 0, stream>>>(
      eWih_f, EE, 0, EE, 320, 2048, 2048, 0, Wihf2);
  k_split_pad<<<dim3((2048 * 320 + 255) / 256), b256, 0, stream>>>(
      eWih_b, EE, 0, EE, 320, 2048, 2048, 0, Wihb2);
  k_gsplit<0><<<dim3(16, 25), b256, 0, stream>>>(xsf, Wihf2, eb_f, xW_f, 3200, 2048, 2048, 320);
  k_gsplit<0><<<dim3(16, 25), b256, 0, stream>>>(xsb, Wihb2, eb_b, xW_b, 3200, 2048, 2048, 320);

  // ---- persistent encoder ----
  {
    void* args[] = {(void*)&xW_f, (void*)&xW_b, (void*)&eWhh_f, (void*)&eWhh_b,
                    (void*)&hs, (void*)&hA, (void*)&hB, (void*)&hA2, (void*)&hB2,
                    (void*)&cf, (void*)&cb, (void*)&hd0, (void*)&hT0, (void*)&cd,
                    (void*)&bar};
    hipLaunchCooperativeKernel((const void*)persist_enc, dim3(256), dim3(512),
                               args, 0, stream);
  }

  // ---- decoder-loop hoists: G = hs@Wi (transposed split), HsWo1(+repack), E_gates ----
  k_split_pad<<<dim3((int)((3200L * 1024 + 255) / 256)), b256, 0, stream>>>(
      hs, DH, 0, DH, 1024, 3200, 3200, 0, hs2);
  k_split_pad<<<dim3((int)((1024L * 1024 + 255) / 256)), b256, 0, stream>>>(
      Wi, DH, 0, DH, 1024, 1024, 1024, 3, Wi2);
  k_split_pad<<<dim3((int)((1024L * 1024 + 255) / 256)), b256, 0, stream>>>(
      Wo, 2 * DH, 0, DH, 1024, 1024, 1024, 0, Wo12);
  k_embgather_split<<<dim3((int)((3200L * 320 + 255) / 256)), b256, 0, stream>>>(
      trg, emb_de, eg2);
  k_split_pad<<<dim3((int)((4096L * 320 + 255) / 256)), b256, 0, stream>>>(
      dWih, 1324, 1024, EE, 320, 4096, 4096, 2, Wce2);
  k_gsplit<0><<<dim3(8, 25), b256, 0, stream>>>(hs2, Wi2, (const float*)nullptr, G, 3200, 1024, 1024, 1024);
  k_gsplit<0><<<dim3(8, 25), b256, 0, stream>>>(hs2, Wo12, (const float*)nullptr, HsWo1, 3200, 1024, 1024, 1024);
  k_repackT<<<dim3((int)((3200L * 1024 + 255) / 256)), b256, 0, stream>>>(HsWo1, HsWo1T);
  k_gsplit<1><<<dim3(32, 25), b256, 0, stream>>>(eg2, Wce2, dbp, E_g, 3136, 4096, 4096, 320);

  // ---- persistent decoder ----
  {
    void* args[] = {(void*)&G, (void*)&HsWo1T, (void*)&Wo, (void*)&dWih, (void*)&dWhh,
                    (void*)&E_g, (void*)&hd0, (void*)&hd1, (void*)&hT0, (void*)&hT1,
                    (void*)&cd, (void*)&attw, (void*)&ctb, (void*)&A_bf, (void*)&bar};
    hipLaunchCooperativeKernel((const void*)persist_dec, dim3(256), dim3(512),
                               args, 0, stream);
  }

  // ---- generator ----
  k_tobf16_pad<<<dim3((int)(((long)GNP * GK + 255) / 256)), b256, 0, stream>>>(
      Wgen, Wgen_bf, GNRE, GNP, GK);
  k_gen_mfma<<<dim3(GNP / 128, GMP / 128), b256, 0, stream>>>(
      A_bf, Wgen_bf, bgen, out + (long)BB * TRGV);
  k_logsoftmax<<<dim3((TT - 1) * BB), b256, 0, stream>>>(out);
}

// Round 9
// 7569.966 us; speedup vs baseline: 3.2616x; 1.2907x over previous
//
#include <hip/hip_runtime.h>
#include <hip/hip_bf16.h>

#define SS 50
#define TT 50
#define BB 64
#define TRGV 23262
#define EE 300
#define EH 512
#define DH 1024

// generator GEMM geometry (bf16 MFMA)
#define GMRE 3136
#define GMP 3200
#define GK 1024
#define GNRE TRGV
#define GNP 23296

typedef short bf16x8 __attribute__((ext_vector_type(8)));
typedef float f32x4 __attribute__((ext_vector_type(4)));

__device__ __forceinline__ void glds16(const void* g, void* l) {
  __builtin_amdgcn_global_load_lds(
      (const __attribute__((address_space(1))) void*)g,
      (__attribute__((address_space(3))) void*)l, 16, 0, 0);
}

__device__ __forceinline__ float sigm(float x) { return 1.f / (1.f + expf(-x)); }
__device__ __forceinline__ float sum4(f32x4 v) { return v[0] + v[1] + v[2] + v[3]; }

__device__ __forceinline__ void split2(float x, __hip_bfloat16& hi, __hip_bfloat16& lo) {
  hi = __float2bfloat16(x);
  lo = __float2bfloat16(x - __bfloat162float(hi));
}

// ---- flag-array grid barrier: O(1)-contention arrivals, parallel poll ----
// arrive[256] + gen, all zeroed per launch. Arrival: one release-store per
// block to its OWN slot (no RMW serialization). Block 0: 256 threads poll the
// 256 slots in parallel (relaxed spin, one acquire), then release-publish gen.
// All blocks spin on gen (read-only broadcast). Release/acquire chain:
// writer block B data -> release arrive[B] -> acquire by block0 poller ->
// (__syncthreads) -> release gen -> acquire by spinning block. Monotone ">="
// comparisons make successive barriers safe (no reset needed; ~200 uses).
__device__ __forceinline__ void gbar(unsigned* arrive, unsigned* gen, int nblk) {
  __syncthreads();
  unsigned g = __hip_atomic_load(gen, __ATOMIC_RELAXED, __HIP_MEMORY_SCOPE_AGENT);
  if (threadIdx.x == 0)
    __hip_atomic_store(arrive + blockIdx.x, g + 1u, __ATOMIC_RELEASE, __HIP_MEMORY_SCOPE_AGENT);
  if (blockIdx.x == 0) {
    int i = threadIdx.x;
    if (i < nblk) {
      while (__hip_atomic_load(arrive + i, __ATOMIC_RELAXED, __HIP_MEMORY_SCOPE_AGENT) < g + 1u)
        __builtin_amdgcn_s_sleep(1);
      (void)__hip_atomic_load(arrive + i, __ATOMIC_ACQUIRE, __HIP_MEMORY_SCOPE_AGENT);
    }
    __syncthreads();
    if (threadIdx.x == 0)
      __hip_atomic_store(gen, g + 1u, __ATOMIC_RELEASE, __HIP_MEMORY_SCOPE_AGENT);
  }
  if (threadIdx.x == 0) {
    while (__hip_atomic_load(gen, __ATOMIC_RELAXED, __HIP_MEMORY_SCOPE_AGENT) < g + 1u)
      __builtin_amdgcn_s_sleep(1);
    (void)__hip_atomic_load(gen, __ATOMIC_ACQUIRE, __HIP_MEMORY_SCOPE_AGENT);
  }
  __syncthreads();
}

__global__ void k_zero(float* __restrict__ p, long n) {
  long i = (long)blockIdx.x * 256 + threadIdx.x;
  if (i < n) p[i] = 0.f;
}
__global__ void k_zero_bf(__hip_bfloat16* __restrict__ p, long n) {
  long i = (long)blockIdx.x * 256 + threadIdx.x;
  if (i < n) p[i] = __float2bfloat16(0.f);
}

__global__ void k_embed(const int* __restrict__ src, const float* __restrict__ emb,
                        float* __restrict__ x) {
  int id = blockIdx.x * 256 + threadIdx.x;
  if (id >= SS * BB * EE) return;
  int sb = id / EE, e = id % EE;
  x[id] = emb[(long)src[sb] * EE + e];
}

__global__ void k_dbperm(const float* __restrict__ db, float* __restrict__ dbp) {
  int id = blockIdx.x * 256 + threadIdx.x;
  if (id >= 4096) return;
  int u = id >> 2, g = id & 3;
  dbp[id] = db[g * 1024 + u];
}

// fp32 [rows][ld] (+col_off) -> [rows_pad][2*Kpad] bf16 hi|lo, zero pad.
// mode 0: src=r ; 1: seq-reverse per 64 ; 2: gate-perm rp=4u+g <- g*1024+u ; 3: transpose
__global__ void k_split_pad(const float* __restrict__ in, int ld_in, int col_off,
                            int Kreal, int Kpad, int rows_real, long rows_pad,
                            int mode, __hip_bfloat16* __restrict__ out) {
  long id = (long)blockIdx.x * 256 + threadIdx.x;
  if (id >= rows_pad * Kpad) return;
  long r = id / Kpad;
  int k = id % Kpad;
  float v = 0.f;
  if (r < rows_real && k < Kreal) {
    if (mode == 3) {
      v = in[(long)k * ld_in + col_off + r];
    } else {
      long sr = r;
      if (mode == 1) sr = ((49 - (r >> 6)) << 6) + (r & 63);
      else if (mode == 2) sr = (long)(r & 3) * 1024 + (r >> 2);
      v = in[sr * ld_in + col_off + k];
    }
  }
  __hip_bfloat16 hi, lo;
  split2(v, hi, lo);
  out[r * 2 * Kpad + k] = hi;
  out[r * 2 * Kpad + Kpad + k] = lo;
}

// gather emb_de[trg[t,b]] -> split [3200][2*320]
__global__ void k_embgather_split(const int* __restrict__ trg, const float* __restrict__ emb,
                                  __hip_bfloat16* __restrict__ out) {
  long id = (long)blockIdx.x * 256 + threadIdx.x;
  if (id >= 3200L * 320) return;
  long r = id / 320;
  int k = id % 320;
  int t = r >> 6, b = r & 63;
  float v = 0.f;
  if (t < TT - 1 && k < EE) v = emb[(long)trg[t * BB + b] * EE + k];
  __hip_bfloat16 hi, lo;
  split2(v, hi, lo);
  out[r * 640 + k] = hi;
  out[r * 640 + 320 + k] = lo;
}

// plain bf16 with zero row padding (generator weight)
__global__ void k_tobf16_pad(const float* __restrict__ W, __hip_bfloat16* __restrict__ Wb,
                             long nrow_real, long nrow_pad, int K) {
  long id = (long)blockIdx.x * 256 + threadIdx.x;
  if (id >= nrow_pad * K) return;
  long r = id / K;
  Wb[id] = __float2bfloat16(r < nrow_real ? W[id] : 0.f);
}

// repack HsWo1 [3200][1024] -> HsWo1T [256 colblk][3200 row][4]
__global__ void k_repackT(const float* __restrict__ in, float* __restrict__ out) {
  long id = (long)blockIdx.x * 256 + threadIdx.x;
  if (id >= 3200L * 1024) return;
  long r = id >> 10;
  int n = id & 1023;
  out[((long)(n >> 2) * 3200 + r) * 4 + (n & 3)] = in[id];
}

// ---- generic split-bf16 MFMA GEMM (3-pass: AhWh + AlWh + AhWl), 128x128 tile ----
template<int OUTBF>
__global__ __launch_bounds__(256) void k_gsplit(
    const __hip_bfloat16* __restrict__ A2, const __hip_bfloat16* __restrict__ W2,
    const float* __restrict__ bias, void* __restrict__ Cout,
    int Mreal, int Nreal, int ldc, int Kpad) {
  __shared__ __hip_bfloat16 As[128 * 32];
  __shared__ __hip_bfloat16 Bs[128 * 32];
  int tid = threadIdx.x, lane = tid & 63, w = tid >> 6;
  long m0 = (long)blockIdx.y * 128, n0 = (long)blockIdx.x * 128;
  int lda2 = 2 * Kpad;
  int srow = lane >> 2;
  int scol = (lane & 3) * 8;
  char* lA0 = (char*)As + w * 2048;
  char* lA1 = lA0 + 1024;
  char* lB0 = (char*)Bs + w * 2048;
  char* lB1 = lB0 + 1024;
  int wm = (w >> 1) * 64, wn = (w & 1) * 64;
  int fr = lane & 15;
  int kc = (lane >> 4) * 8;
  f32x4 acc[4][4] = {};

  for (int seg = 0; seg < 3; ++seg) {
    const __hip_bfloat16* Ab = A2 + (seg == 1 ? Kpad : 0);
    const __hip_bfloat16* Wb = W2 + (seg == 2 ? Kpad : 0);
    const __hip_bfloat16* gA0 = Ab + (m0 + w * 32 + srow) * (long)lda2 + scol;
    const __hip_bfloat16* gA1 = gA0 + 16L * lda2;
    const __hip_bfloat16* gB0 = Wb + (n0 + w * 32 + srow) * (long)lda2 + scol;
    const __hip_bfloat16* gB1 = gB0 + 16L * lda2;
    for (int kt = 0; kt < Kpad / 32; ++kt) {
      int k0 = kt * 32;
      glds16(gA0 + k0, lA0);
      glds16(gA1 + k0, lA1);
      glds16(gB0 + k0, lB0);
      glds16(gB1 + k0, lB1);
      __syncthreads();
      bf16x8 a[4], b[4];
      for (int mi = 0; mi < 4; ++mi)
        a[mi] = *(const bf16x8*)(As + (wm + mi * 16 + fr) * 32 + kc);
      for (int ni = 0; ni < 4; ++ni)
        b[ni] = *(const bf16x8*)(Bs + (wn + ni * 16 + fr) * 32 + kc);
      for (int mi = 0; mi < 4; ++mi)
        for (int ni = 0; ni < 4; ++ni)
          acc[mi][ni] = __builtin_amdgcn_mfma_f32_16x16x32_bf16(a[mi], b[ni], acc[mi][ni], 0, 0, 0);
      __syncthreads();
    }
  }

  for (int mi = 0; mi < 4; ++mi) {
    for (int ni = 0; ni < 4; ++ni) {
      int n = (int)n0 + wn + ni * 16 + (lane & 15);
      if (n >= Nreal) continue;
      float bv = bias ? bias[n] : 0.f;
      for (int r = 0; r < 4; ++r) {
        int m = (int)m0 + wm + mi * 16 + (lane >> 4) * 4 + r;
        if (m >= Mreal) continue;
        float v = acc[mi][ni][r] + bv;
        if (OUTBF) ((__hip_bfloat16*)Cout)[(long)m * ldc + n] = __float2bfloat16(v);
        else ((float*)Cout)[(long)m * ldc + n] = v;
      }
    }
  }
}

// ---- persistent encoder: Whh in LDS, 1 flag-barrier/step ----
__global__ __launch_bounds__(512) void persist_enc(
    const float* __restrict__ xW_f, const float* __restrict__ xW_b,
    const float* __restrict__ Whf, const float* __restrict__ Whb,
    float* __restrict__ hs, float* hA, float* hB, float* hA2, float* hB2,
    float* __restrict__ cf, float* __restrict__ cb,
    float* __restrict__ hd0, float* __restrict__ hT0, float* __restrict__ cdD,
    unsigned* __restrict__ bar) {
  __shared__ float WL[16 * 516];
  int t = threadIdx.x;
  int blk = blockIdx.x;
  int dir = blk >> 7, bl = blk & 127;
  const float* Whh = dir ? Whb : Whf;
  const float* xWb0 = dir ? xW_b : xW_f;
  float* c = dir ? cb : cf;
  float* hp = dir ? hA2 : hA;
  float* hn = dir ? hB2 : hB;
  unsigned* arrive = bar;
  unsigned* gen = bar + 256;

  for (int idx = t; idx < 16 * 512; idx += 512) {
    int r = idx >> 9, k = idx & 511;
    int srcrow = (r & 3) * 512 + (bl * 4 + (r >> 2));
    WL[r * 516 + k] = Whh[(long)srcrow * 512 + k];
  }
  __syncthreads();

  int j = t & 15;
  int b0 = t >> 4, b1 = b0 + 32;
  int g = j & 3;
  int ju = bl * 4 + (j >> 2);
  int lbase = (t & 63) & ~3;
  const f32x4* wq = (const f32x4*)(WL + j * 516);

  for (int s = 0; s < SS; ++s) {
    const f32x4* h0q = (const f32x4*)(hp + b0 * 512);
    const f32x4* h1q = (const f32x4*)(hp + b1 * 512);
    f32x4 v0 = {0, 0, 0, 0}, v1 = {0, 0, 0, 0};
    for (int q = 0; q < 128; ++q) {
      f32x4 wv = wq[q];
      v0 += wv * h0q[q];
      v1 += wv * h1q[q];
    }
    const float* xW = xWb0 + (long)(s * BB) * 2048;
    float a0 = sum4(v0) + xW[b0 * 2048 + g * 512 + ju];
    float a1 = sum4(v1) + xW[b1 * 2048 + g * 512 + ju];
    float gi0 = __shfl(a0, lbase + 0), gf0 = __shfl(a0, lbase + 1);
    float gg0 = __shfl(a0, lbase + 2), go0 = __shfl(a0, lbase + 3);
    float gi1 = __shfl(a1, lbase + 0), gf1 = __shfl(a1, lbase + 1);
    float gg1 = __shfl(a1, lbase + 2), go1 = __shfl(a1, lbase + 3);
    if ((t & 3) == 0) {
      int hscol = dir ? (512 + ju) : ju;
      int srow = dir ? (SS - 1 - s) : s;
      long hsrow0 = (long)(srow * BB + b0) * DH + hscol;
      long hsrow1 = (long)(srow * BB + b1) * DH + hscol;
      float cn0 = sigm(gf0) * c[b0 * 512 + ju] + sigm(gi0) * tanhf(gg0);
      float hn0 = sigm(go0) * tanhf(cn0);
      c[b0 * 512 + ju] = cn0;
      hn[b0 * 512 + ju] = hn0;
      hs[hsrow0] = hn0;
      float cn1 = sigm(gf1) * c[b1 * 512 + ju] + sigm(gi1) * tanhf(gg1);
      float hn1 = sigm(go1) * tanhf(cn1);
      c[b1 * 512 + ju] = cn1;
      hn[b1 * 512 + ju] = hn1;
      hs[hsrow1] = hn1;
    }
    float* tmp = hp; hp = hn; hn = tmp;
    gbar(arrive, gen, 256);
  }
  int gid = blk * 512 + t;
  if (gid < 65536) {
    int d2 = gid >> 15, b = (gid >> 9) & 63, j2 = gid & 511;
    float hv = (d2 ? hA2 : hA)[b * 512 + j2];
    float cv = (d2 ? cb : cf)[b * 512 + j2];
    hd0[gid] = hv;
    cdD[gid] = cv;
    int bp = gid >> 10, jp = gid & 1023;
    hT0[jp * 64 + bp] = hv;
  }
}

// ---- persistent decoder: Wc13 + Wo2 pinned in LDS, 3 flag-barriers/step ----
__global__ __launch_bounds__(512) void persist_dec(
    const float* __restrict__ G, const float* __restrict__ HsWo1T,
    const float* __restrict__ Wo, const float* __restrict__ dWih,
    const float* __restrict__ dWhh, const __hip_bfloat16* __restrict__ Eg,
    float* hd0, float* hd1, float* hT0, float* hT1,
    float* __restrict__ cd, float* __restrict__ attw, float* __restrict__ ctb,
    __hip_bfloat16* __restrict__ A_bf, unsigned* __restrict__ bar) {
  __shared__ float WcL[16 * 2052];
  __shared__ float WoL[4 * 1028];
  __shared__ float red[2048];
  int t = threadIdx.x;
  int blk = blockIdx.x;
  int w = t >> 6, lane = t & 63;
  unsigned* arrive = bar;
  unsigned* gen = bar + 256;

  for (int idx = t; idx < 16 * 2048; idx += 512) {
    int r = idx >> 11, k = idx & 2047;
    int rp2 = blk * 16 + r;
    long srcrow = (long)(rp2 & 3) * 1024 + (rp2 >> 2);
    float v = (k < 1024) ? dWih[srcrow * 1324 + k] : dWhh[srcrow * 1024 + (k - 1024)];
    WcL[r * 2052 + k] = v;
  }
  for (int idx = t; idx < 4 * 1024; idx += 512) {
    int r = idx >> 10, k = idx & 1023;
    WoL[r * 1028 + k] = Wo[(long)(blk * 4 + r) * 2048 + 1024 + k];
  }
  __syncthreads();

  float* hcur = hd0; float* hnew = hd1;
  float* hTc = hT0;  float* hTn = hT1;
  int j = t & 15;
  int b0 = t >> 4, b1 = b0 + 32;
  int rp = blk * 16 + j;
  int ju = blk * 4 + (j >> 2);
  int lbase = (t & 63) & ~3;
  const f32x4* hw = (const f32x4*)(HsWo1T + (long)blk * 3200 * 4);

  for (int ts = 0; ts < TT - 1; ++ts) {
    // ---- Phase S: scores[s,b] = h[b,:]·G[s,b,:], softmax over b ----
    if (blk < SS) {
      int s = blk;
      const f32x4* gq = (const f32x4*)(G + ((long)(s * BB + lane)) * DH + w * 128);
      const f32x4* hq = (const f32x4*)(hcur + lane * DH + w * 128);
      f32x4 a4 = {0, 0, 0, 0};
      for (int q = 0; q < 32; ++q) a4 += gq[q] * hq[q];
      red[w * 64 + lane] = sum4(a4);
      __syncthreads();
      if (w == 0) {
        float sc = 0.f;
        for (int i = 0; i < 8; ++i) sc += red[i * 64 + lane];
        float m = sc;
        for (int o = 32; o > 0; o >>= 1) m = fmaxf(m, __shfl_xor(m, o));
        float e = expf(sc - m);
        float su = e;
        for (int o = 32; o > 0; o >>= 1) su += __shfl_xor(su, o);
        attw[s * BB + lane] = e / su;
      }
    }
    gbar(arrive, gen, 256);
    // ---- Phase TC: ct[b, blk*4+nl] = tanh( sum_s a*HsWo1T + h@Wo2 ) ----
    {
      int n0 = blk * 4;
      f32x4 z = {0, 0, 0, 0};
      for (int s = w; s < SS; s += 8) {
        float aw = attw[s * BB + lane];
        f32x4 hv = hw[s * 64 + lane];
        z += aw * hv;
      }
      for (int k = w * 128; k < w * 128 + 128; ++k) {
        float hb = hTc[k * 64 + lane];
        f32x4 wv = {WoL[0 * 1028 + k], WoL[1 * 1028 + k], WoL[2 * 1028 + k], WoL[3 * 1028 + k]};
        z += hb * wv;
      }
      red[w * 256 + lane * 4 + 0] = z[0];
      red[w * 256 + lane * 4 + 1] = z[1];
      red[w * 256 + lane * 4 + 2] = z[2];
      red[w * 256 + lane * 4 + 3] = z[3];
      __syncthreads();
      if (t < 256) {
        int b = t >> 2, nl = t & 3;
        float sv = 0.f;
        for (int i = 0; i < 8; ++i) sv += red[i * 256 + b * 4 + nl];
        ctb[b * DH + n0 + nl] = tanhf(sv);
      }
    }
    gbar(arrive, gen, 256);
    // ---- Phase G: gates + LSTM pointwise ----
    {
      const f32x4* wq1 = (const f32x4*)(WcL + j * 2052);
      const f32x4* wq2 = (const f32x4*)(WcL + j * 2052 + 1024);
      const f32x4* c0q = (const f32x4*)(ctb + b0 * DH);
      const f32x4* c1q = (const f32x4*)(ctb + b1 * DH);
      const f32x4* h0q = (const f32x4*)(hcur + b0 * DH);
      const f32x4* h1q = (const f32x4*)(hcur + b1 * DH);
      f32x4 v0 = {0, 0, 0, 0}, v1 = {0, 0, 0, 0};
      for (int q = 0; q < 256; ++q) {
        f32x4 wv = wq1[q];
        v0 += wv * c0q[q];
        v1 += wv * c1q[q];
      }
      for (int q = 0; q < 256; ++q) {
        f32x4 wv = wq2[q];
        v0 += wv * h0q[q];
        v1 += wv * h1q[q];
      }
      float a0 = sum4(v0) + __bfloat162float(Eg[((long)(ts * BB + b0)) * 4096 + rp]);
      float a1 = sum4(v1) + __bfloat162float(Eg[((long)(ts * BB + b1)) * 4096 + rp]);
      float gi0 = __shfl(a0, lbase + 0), gf0 = __shfl(a0, lbase + 1);
      float gg0 = __shfl(a0, lbase + 2), go0 = __shfl(a0, lbase + 3);
      float gi1 = __shfl(a1, lbase + 0), gf1 = __shfl(a1, lbase + 1);
      float gg1 = __shfl(a1, lbase + 2), go1 = __shfl(a1, lbase + 3);
      if ((t & 3) == 0) {
        float cn0 = sigm(gf0) * cd[b0 * DH + ju] + sigm(gi0) * tanhf(gg0);
        float hn0 = sigm(go0) * tanhf(cn0);
        cd[b0 * DH + ju] = cn0;
        hnew[b0 * DH + ju] = hn0;
        hTn[ju * 64 + b0] = hn0;
        A_bf[(long)ts * (BB * DH) + b0 * DH + ju] = __float2bfloat16(hn0);
        float cn1 = sigm(gf1) * cd[b1 * DH + ju] + sigm(gi1) * tanhf(gg1);
        float hn1 = sigm(go1) * tanhf(cn1);
        cd[b1 * DH + ju] = cn1;
        hnew[b1 * DH + ju] = hn1;
        hTn[ju * 64 + b1] = hn1;
        A_bf[(long)ts * (BB * DH) + b1 * DH + ju] = __float2bfloat16(hn1);
      }
    }
    { float* x = hcur; hcur = hnew; hnew = x; }
    { float* x = hTc; hTc = hTn; hTn = x; }
    gbar(arrive, gen, 256);
  }
}

// ---- bf16 MFMA generator GEMM (128x128 tile, m97 structure) ----
__global__ __launch_bounds__(256) void k_gen_mfma(
    const __hip_bfloat16* __restrict__ A, const __hip_bfloat16* __restrict__ Bw,
    const float* __restrict__ bias, float* __restrict__ C) {
  __shared__ __hip_bfloat16 As[128 * 32];
  __shared__ __hip_bfloat16 Bs[128 * 32];
  int tid = threadIdx.x;
  int lane = tid & 63, w = tid >> 6;
  long m0 = (long)blockIdx.y * 128, n0 = (long)blockIdx.x * 128;
  int srow = lane >> 2;
  int scol = (lane & 3) * 8;
  const __hip_bfloat16* gA0 = A + (m0 + w * 32 + srow) * GK + scol;
  const __hip_bfloat16* gA1 = gA0 + 16 * GK;
  const __hip_bfloat16* gB0 = Bw + (n0 + w * 32 + srow) * GK + scol;
  const __hip_bfloat16* gB1 = gB0 + 16 * GK;
  char* lA0 = (char*)As + w * 2048;
  char* lA1 = lA0 + 1024;
  char* lB0 = (char*)Bs + w * 2048;
  char* lB1 = lB0 + 1024;
  int wm = (w >> 1) * 64, wn = (w & 1) * 64;
  int fr = lane & 15;
  int kc = (lane >> 4) * 8;
  f32x4 acc[4][4] = {};
  for (int kt = 0; kt < GK / 32; ++kt) {
    int k0 = kt * 32;
    glds16(gA0 + k0, lA0);
    glds16(gA1 + k0, lA1);
    glds16(gB0 + k0, lB0);
    glds16(gB1 + k0, lB1);
    __syncthreads();
    bf16x8 a[4], b[4];
    for (int mi = 0; mi < 4; ++mi)
      a[mi] = *(const bf16x8*)(As + (wm + mi * 16 + fr) * 32 + kc);
    for (int ni = 0; ni < 4; ++ni)
      b[ni] = *(const bf16x8*)(Bs + (wn + ni * 16 + fr) * 32 + kc);
    for (int mi = 0; mi < 4; ++mi)
      for (int ni = 0; ni < 4; ++ni)
        acc[mi][ni] = __builtin_amdgcn_mfma_f32_16x16x32_bf16(a[mi], b[ni], acc[mi][ni], 0, 0, 0);
    __syncthreads();
  }
  for (int mi = 0; mi < 4; ++mi) {
    for (int ni = 0; ni < 4; ++ni) {
      int n = (int)n0 + wn + ni * 16 + (lane & 15);
      if (n >= GNRE) continue;
      float bv = bias[n];
      for (int r = 0; r < 4; ++r) {
        int m = (int)m0 + wm + mi * 16 + (lane >> 4) * 4 + r;
        if (m < GMRE) C[(long)m * TRGV + n] = acc[mi][ni][r] + bv;
      }
    }
  }
}

// in-place log-softmax over vocab for rows 64..3199 of out
__global__ __launch_bounds__(256) void k_logsoftmax(float* __restrict__ out) {
  int r = blockIdx.x;
  float* p = out + (long)(BB + r) * TRGV;
  int tid = threadIdx.x;
  __shared__ float red[256];
  float m = -1e30f;
  for (int i = tid; i < TRGV; i += 256) m = fmaxf(m, p[i]);
  red[tid] = m;
  __syncthreads();
  for (int s = 128; s > 0; s >>= 1) {
    if (tid < s) red[tid] = fmaxf(red[tid], red[tid + s]);
    __syncthreads();
  }
  m = red[0];
  __syncthreads();
  float sum = 0.f;
  for (int i = tid; i < TRGV; i += 256) sum += expf(p[i] - m);
  red[tid] = sum;
  __syncthreads();
  for (int s = 128; s > 0; s >>= 1) {
    if (tid < s) red[tid] += red[tid + s];
    __syncthreads();
  }
  float lse = m + logf(red[0]);
  for (int i = tid; i < TRGV; i += 256) p[i] -= lse;
}

extern "C" void kernel_launch(void* const* d_in, const int* in_sizes, int n_in,
                              void* d_out, int out_size, void* d_ws, size_t ws_size,
                              hipStream_t stream) {
  const int* src = (const int*)d_in[0];
  const int* trg = (const int*)d_in[1];
  const float* emb_en = (const float*)d_in[2];
  const float* emb_de = (const float*)d_in[3];
  const float* eWih_f = (const float*)d_in[4];
  const float* eWhh_f = (const float*)d_in[5];
  const float* eb_f = (const float*)d_in[6];
  const float* eWih_b = (const float*)d_in[7];
  const float* eWhh_b = (const float*)d_in[8];
  const float* eb_b = (const float*)d_in[9];
  const float* dWih = (const float*)d_in[10];
  const float* dWhh = (const float*)d_in[11];
  const float* db = (const float*)d_in[12];
  const float* Wgen = (const float*)d_in[13];
  const float* bgen = (const float*)d_in[14];
  const float* Wi = (const float*)d_in[15];
  const float* Wo = (const float*)d_in[16];
  float* out = (float*)d_out;

  float* base = (float*)d_ws;
  // ---- region RA (16,465,920 floats, time-multiplexed) ----
  __hip_bfloat16* xsf = (__hip_bfloat16*)base;
  __hip_bfloat16* xsb = (__hip_bfloat16*)(base + 1024000);
  __hip_bfloat16* Wihf2 = (__hip_bfloat16*)(base + 2048000);
  __hip_bfloat16* Wihb2 = (__hip_bfloat16*)(base + 2703360);
  float* xW_f = base + 3358720;
  float* xW_b = base + 9912320;
  __hip_bfloat16* hs2 = (__hip_bfloat16*)base;
  __hip_bfloat16* Wi2 = (__hip_bfloat16*)(base + 3276800);
  __hip_bfloat16* Wo12 = (__hip_bfloat16*)(base + 4325376);
  __hip_bfloat16* eg2 = (__hip_bfloat16*)(base + 5373952);
  __hip_bfloat16* Wce2 = (__hip_bfloat16*)(base + 6397952);
  __hip_bfloat16* E_g = (__hip_bfloat16*)(base + 7708672);
  __hip_bfloat16* Wgen_bf = (__hip_bfloat16*)base;   // phase 3
  // ---- region RB (persistent) ----
  float* p = base + 16465920;
  float* x_enc = p; p += SS * BB * EE;
  float* hs = p; p += (long)SS * BB * DH;
  float* G = p; p += (long)SS * BB * DH;
  float* HsWo1 = p; p += (long)SS * BB * DH;
  float* HsWo1T = p; p += (long)SS * BB * DH;
  __hip_bfloat16* A_bf = (__hip_bfloat16*)p; p += (GMP * GK) / 2;
  float* dbp = p; p += 4096;
  float* attw = p; p += SS * BB;
  float* hd0 = p; p += BB * DH;
  float* hd1 = p; p += BB * DH;
  float* hT0 = p; p += BB * DH;
  float* hT1 = p; p += BB * DH;
  float* cd = p; p += BB * DH;
  float* ctb = p; p += BB * DH;
  float* hA = p; p += BB * EH;
  float* hB = p; p += BB * EH;
  float* hA2 = p; p += BB * EH;
  float* hB2 = p; p += BB * EH;
  float* cf = p; p += BB * EH;
  float* cb = p; p += BB * EH;
  unsigned* bar = (unsigned*)p; p += 512;   // arrive[256] @0, gen @256

  dim3 b256(256);

  // ---- setup ----
  k_embed<<<dim3((SS * BB * EE + 255) / 256), b256, 0, stream>>>(src, emb_en, x_enc);
  k_zero<<<dim3((6 * BB * EH + 255) / 256), b256, 0, stream>>>(hA, 6 * BB * EH);
  k_zero<<<dim3(2), b256, 0, stream>>>((float*)bar, 512);
  k_zero<<<dim3((int)(((long)BB * TRGV + 255) / 256)), b256, 0, stream>>>(out, (long)BB * TRGV);
  k_zero_bf<<<dim3(((GMP - GMRE) * GK + 255) / 256), b256, 0, stream>>>(
      A_bf + (long)GMRE * GK, (long)(GMP - GMRE) * GK);
  k_dbperm<<<dim3(16), b256, 0, stream>>>(db, dbp);

  // ---- encoder input: splits + split-MFMA GEMMs ----
  k_split_pad<<<dim3((3200 * 320 + 255) / 256), b256, 0, stream>>>(
      x_enc, EE, 0, EE, 320, 3200, 3200, 0, xsf);
  k_split_pad<<<dim3((3200 * 320 + 255) / 256), b256, 0, stream>>>(
      x_enc, EE, 0, EE, 320, 3200, 3200, 1, xsb);
  k_split_pad<<<dim3((2048 * 320 + 255) / 256), b256, 0, stream>>>(
      eWih_f, EE, 0, EE, 320, 2048, 2048, 0, Wihf2);
  k_split_pad<<<dim3((2048 * 320 + 255) / 256), b256, 0, stream>>>(
      eWih_b, EE, 0, EE, 320, 2048, 2048, 0, Wihb2);
  k_gsplit<0><<<dim3(16, 25), b256, 0, stream>>>(xsf, Wihf2, eb_f, xW_f, 3200, 2048, 2048, 320);
  k_gsplit<0><<<dim3(16, 25), b256, 0, stream>>>(xsb, Wihb2, eb_b, xW_b, 3200, 2048, 2048, 320);

  // ---- persistent encoder ----
  {
    void* args[] = {(void*)&xW_f, (void*)&xW_b, (void*)&eWhh_f, (void*)&eWhh_b,
                    (void*)&hs, (void*)&hA, (void*)&hB, (void*)&hA2, (void*)&hB2,
                    (void*)&cf, (void*)&cb, (void*)&hd0, (void*)&hT0, (void*)&cd,
                    (void*)&bar};
    hipLaunchCooperativeKernel((const void*)persist_enc, dim3(256), dim3(512),
                               args, 0, stream);
  }

  // ---- decoder-loop hoists: G = hs@Wi (transposed split), HsWo1(+repack), E_gates ----
  k_split_pad<<<dim3((int)((3200L * 1024 + 255) / 256)), b256, 0, stream>>>(
      hs, DH, 0, DH, 1024, 3200, 3200, 0, hs2);
  k_split_pad<<<dim3((int)((1024L * 1024 + 255) / 256)), b256, 0, stream>>>(
      Wi, DH, 0, DH, 1024, 1024, 1024, 3, Wi2);
  k_split_pad<<<dim3((int)((1024L * 1024 + 255) / 256)), b256, 0, stream>>>(
      Wo, 2 * DH, 0, DH, 1024, 1024, 1024, 0, Wo12);
  k_embgather_split<<<dim3((int)((3200L * 320 + 255) / 256)), b256, 0, stream>>>(
      trg, emb_de, eg2);
  k_split_pad<<<dim3((int)((4096L * 320 + 255) / 256)), b256, 0, stream>>>(
      dWih, 1324, 1024, EE, 320, 4096, 4096, 2, Wce2);
  k_gsplit<0><<<dim3(8, 25), b256, 0, stream>>>(hs2, Wi2, (const float*)nullptr, G, 3200, 1024, 1024, 1024);
  k_gsplit<0><<<dim3(8, 25), b256, 0, stream>>>(hs2, Wo12, (const float*)nullptr, HsWo1, 3200, 1024, 1024, 1024);
  k_repackT<<<dim3((int)((3200L * 1024 + 255) / 256)), b256, 0, stream>>>(HsWo1, HsWo1T);
  k_gsplit<1><<<dim3(32, 25), b256, 0, stream>>>(eg2, Wce2, dbp, E_g, 3136, 4096, 4096, 320);

  // ---- persistent decoder ----
  {
    void* args[] = {(void*)&G, (void*)&HsWo1T, (void*)&Wo, (void*)&dWih, (void*)&dWhh,
                    (void*)&E_g, (void*)&hd0, (void*)&hd1, (void*)&hT0, (void*)&hT1,
                    (void*)&cd, (void*)&attw, (void*)&ctb, (void*)&A_bf, (void*)&bar};
    hipLaunchCooperativeKernel((const void*)persist_dec, dim3(256), dim3(512),
                               args, 0, stream);
  }

  // ---- generator ----
  k_tobf16_pad<<<dim3((int)(((long)GNP * GK + 255) / 256)), b256, 0, stream>>>(
      Wgen, Wgen_bf, GNRE, GNP, GK);
  k_gen_mfma<<<dim3(GNP / 128, GMP / 128), b256, 0, stream>>>(
      A_bf, Wgen_bf, bgen, out + (long)BB * TRGV);
  k_logsoftmax<<<dim3((TT - 1) * BB), b256, 0, stream>>>(out);
}